// Round 5
// baseline (1064.284 us; speedup 1.0000x reference)
//
#include <hip/hip_runtime.h>
#include <hip/hip_bf16.h>
#include <math.h>

#define L_SEQ 8192
#define NFFT  16384
#define NZ    16896   // NFFT + NFFT/32 pad, in float2 units (135168 B LDS)
#define F_DIM 768
#define D_DIM 768
#define C_IN  2304    // INNER = F*(ORDER+1)
#define NORD  2
#define NT_FFT 1024   // 16 waves/CU: latency hiding at 1 block/CU
#define TWO_PI 6.2831853071795864769f

typedef unsigned short u16;
typedef __attribute__((ext_vector_type(8))) short bf16x8;
typedef __attribute__((ext_vector_type(4))) float f32x4;
struct __align__(8) U16x4 { u16 x, y, z, w; };

__device__ __forceinline__ float bf2f(u16 v) {
  unsigned u = ((unsigned)v) << 16; float f; __builtin_memcpy(&f, &u, 4); return f;
}
__device__ __forceinline__ u16 f2bf(float f) {
  __hip_bfloat16 h = __float2bfloat16(f); u16 r; __builtin_memcpy(&r, &h, 2); return r;
}

// complex index -> padded float2 index: 1 extra complex per 32 keeps all
// observed lane patterns <=2-way bank aliasing (free).
__device__ __forceinline__ int IDX(int i) { return i + (i >> 5); }

__device__ __forceinline__ void rot3(float ang, float& c1, float& s1,
                                     float& c2, float& s2, float& c3, float& s3)
{
  __sincosf(ang, &s1, &c1);
  c2 = c1 * c1 - s1 * s1; s2 = 2.0f * c1 * s1;
  c3 = c1 * c2 - s1 * s2; s3 = c1 * s2 + s1 * c2;
}

// ===========================================================================
// Radix-4 FFT, N = 16384 = 4^7, complex interleaved float2 in LDS (b64 ops).
// fwd: DIF pairs (12,10)(8,6)(4,2) + final quad; natural -> digit-reversed.
// inv: head quad + DIT pairs (2,4)(6,8)(10,12); digit-reversed -> natural,
// UNNORMALIZED. Stage algebra verbatim from the verified round-0 version.
// ===========================================================================

// layer-2 (stage 10) + stores of the first fwd pair; shared by all stage-1
// variants. g in [0,1024): base=j=g, q=4096, q4=1024.
__device__ __forceinline__ void stage1_layer2_store(float2* z, int g,
    const float yr[4][4], const float yi4[4][4])
{
  const float stw2 = -TWO_PI / 4096.0f;
  float c1, s1, c2, s2, c3, s3;
  rot3(stw2 * (float)g, c1, s1, c2, s2, c3, s3);
  #pragma unroll
  for (int k = 0; k < 4; ++k) {
    float t0r = yr[k][0] + yr[k][2], t0i = yi4[k][0] + yi4[k][2];
    float t1r = yr[k][0] - yr[k][2], t1i = yi4[k][0] - yi4[k][2];
    float t2r = yr[k][1] + yr[k][3], t2i = yi4[k][1] + yi4[k][3];
    float t3r = yr[k][1] - yr[k][3], t3i = yi4[k][1] - yi4[k][3];
    float o0r = t0r + t2r, o0i = t0i + t2i;
    float o1r = t1r + t3i, o1i = t1i - t3r;
    float o2r = t0r - t2r, o2i = t0i - t2i;
    float o3r = t1r - t3i, o3i = t1i + t3r;
    const int i0 = g + (k << 12);
    z[IDX(i0       )] = make_float2(o0r, o0i);
    z[IDX(i0 + 1024)] = make_float2(o1r*c1 - o1i*s1, o1r*s1 + o1i*c1);
    z[IDX(i0 + 2048)] = make_float2(o2r*c2 - o2i*s2, o2r*s2 + o2i*c2);
    z[IDX(i0 + 3072)] = make_float2(o3r*c3 - o3i*s3, o3r*s3 + o3i*c3);
  }
}

// stage-1 layer-1 with k=2,3 inputs == 0 (zero-padded upper half).
// Generic algebra with x2=x3=0: t0=t1=x0, t2=t3=x1.
__device__ __forceinline__ void stage1_tail_zero_hi(float2* z, int g,
    const float xr[2][4], const float xi[2][4])
{
  const float stw1 = -TWO_PI / 16384.0f;
  float yr[4][4], yi4[4][4];
  #pragma unroll
  for (int m = 0; m < 4; ++m) {
    const float x0r = xr[0][m], x0i = xi[0][m];
    const float x1r = xr[1][m], x1i = xi[1][m];
    const float y0r = x0r + x1r, y0i = x0i + x1i;
    const float y1r = x0r + x1i, y1i = x0i - x1r;
    const float y2r = x0r - x1r, y2i = x0i - x1i;
    const float y3r = x0r - x1i, y3i = x0i + x1r;
    float c1, s1, c2, s2, c3, s3;
    rot3(stw1 * (float)(g + (m << 10)), c1, s1, c2, s2, c3, s3);
    yr[0][m] = y0r;               yi4[0][m] = y0i;
    yr[1][m] = y1r*c1 - y1i*s1;   yi4[1][m] = y1r*s1 + y1i*c1;
    yr[2][m] = y2r*c2 - y2i*s2;   yi4[2][m] = y2r*s2 + y2i*c2;
    yr[3][m] = y3r*c3 - y3i*s3;   yi4[3][m] = y3r*s3 + y3i*c3;
  }
  stage1_layer2_store(z, g, yr, yi4);
}

template<int NT>
__device__ __forceinline__ void fwd_mid_pairs(float2* z, int tid)
{
  #pragma unroll
  for (int lq = 8; lq >= 4; lq -= 4) {       // fused pair: stage lq then lq-2
    const int q  = 1 << lq;
    const int q4 = q >> 2;
    const float stw1 = -TWO_PI / (float)(q << 2);
    const float stw2 = -TWO_PI / (float)q;
    for (int g = tid; g < NFFT / 16; g += NT) {
      const int j    = g & (q4 - 1);
      const int base = ((g >> (lq - 2)) << (lq + 2)) + j;
      float xr[4][4], xi4[4][4];
      #pragma unroll
      for (int k = 0; k < 4; ++k)
        #pragma unroll
        for (int m = 0; m < 4; ++m) {
          const float2 v = z[IDX(base + m * q4 + k * q)];
          xr[k][m] = v.x; xi4[k][m] = v.y;
        }
      #pragma unroll
      for (int m = 0; m < 4; ++m) {          // layer 1: stage lq
        float t0r = xr[0][m] + xr[2][m], t0i = xi4[0][m] + xi4[2][m];
        float t1r = xr[0][m] - xr[2][m], t1i = xi4[0][m] - xi4[2][m];
        float t2r = xr[1][m] + xr[3][m], t2i = xi4[1][m] + xi4[3][m];
        float t3r = xr[1][m] - xr[3][m], t3i = xi4[1][m] - xi4[3][m];
        float y0r = t0r + t2r, y0i = t0i + t2i;
        float y1r = t1r + t3i, y1i = t1i - t3r;
        float y2r = t0r - t2r, y2i = t0i - t2i;
        float y3r = t1r - t3i, y3i = t1i + t3r;
        float c1, s1, c2, s2, c3, s3;
        rot3(stw1 * (float)(j + m * q4), c1, s1, c2, s2, c3, s3);
        xr[0][m] = y0r;                xi4[0][m] = y0i;
        xr[1][m] = y1r * c1 - y1i * s1; xi4[1][m] = y1r * s1 + y1i * c1;
        xr[2][m] = y2r * c2 - y2i * s2; xi4[2][m] = y2r * s2 + y2i * c2;
        xr[3][m] = y3r * c3 - y3i * s3; xi4[3][m] = y3r * s3 + y3i * c3;
      }
      float c1, s1, c2, s2, c3, s3;          // layer 2: stage lq-2
      rot3(stw2 * (float)j, c1, s1, c2, s2, c3, s3);
      #pragma unroll
      for (int k = 0; k < 4; ++k) {
        float t0r = xr[k][0] + xr[k][2], t0i = xi4[k][0] + xi4[k][2];
        float t1r = xr[k][0] - xr[k][2], t1i = xi4[k][0] - xi4[k][2];
        float t2r = xr[k][1] + xr[k][3], t2i = xi4[k][1] + xi4[k][3];
        float t3r = xr[k][1] - xr[k][3], t3i = xi4[k][1] - xi4[k][3];
        float y0r = t0r + t2r, y0i = t0i + t2i;
        float y1r = t1r + t3i, y1i = t1i - t3r;
        float y2r = t0r - t2r, y2i = t0i - t2i;
        float y3r = t1r - t3i, y3i = t1i + t3r;
        const int i0 = base + k * q;
        z[IDX(i0         )] = make_float2(y0r, y0i);
        z[IDX(i0 +     q4)] = make_float2(y1r*c1 - y1i*s1, y1r*s1 + y1i*c1);
        z[IDX(i0 + 2 * q4)] = make_float2(y2r*c2 - y2i*s2, y2r*s2 + y2i*c2);
        z[IDX(i0 + 3 * q4)] = make_float2(y3r*c3 - y3i*s3, y3r*s3 + y3i*c3);
      }
    }
    __syncthreads();
  }
}

// fwd final radix-4 (twiddle-free) + spectrum multiply + inv radix-4 head,
// fused in registers: both stages iterate the same quads i0 = 4b.
template<int NT>
__device__ __forceinline__ void fwd_final_spec_inv_head(float2* z,
    const __hip_bfloat162* __restrict__ H, int tid)
{
  for (int b = tid; b < NFFT / 4; b += NT) {
    const int i0 = b << 2;
    const float2 a0 = z[IDX(i0)],     a1 = z[IDX(i0 + 1)];
    const float2 a2 = z[IDX(i0 + 2)], a3 = z[IDX(i0 + 3)];
    // fwd final radix-4
    float t0r = a0.x + a2.x, t0i = a0.y + a2.y;
    float t1r = a0.x - a2.x, t1i = a0.y - a2.y;
    float t2r = a1.x + a3.x, t2i = a1.y + a3.y;
    float t3r = a1.x - a3.x, t3i = a1.y - a3.y;
    float y0r = t0r + t2r, y0i = t0i + t2i;
    float y1r = t1r + t3i, y1i = t1i - t3r;
    float y2r = t0r - t2r, y2i = t0i - t2i;
    float y3r = t1r - t3i, y3i = t1i + t3r;
    // spectrum multiply: 4 bf16x2 in one 16B load
    const float4 hq = *(const float4*)&H[i0];
    __hip_bfloat162 h0, h1, h2, h3;
    __builtin_memcpy(&h0, &hq.x, 4); __builtin_memcpy(&h1, &hq.y, 4);
    __builtin_memcpy(&h2, &hq.z, 4); __builtin_memcpy(&h3, &hq.w, 4);
    float hr, hi;
    hr = __bfloat162float(h0.x); hi = __bfloat162float(h0.y);
    const float u0r = y0r*hr - y0i*hi, u0i = y0r*hi + y0i*hr;
    hr = __bfloat162float(h1.x); hi = __bfloat162float(h1.y);
    const float u1r = y1r*hr - y1i*hi, u1i = y1r*hi + y1i*hr;
    hr = __bfloat162float(h2.x); hi = __bfloat162float(h2.y);
    const float u2r = y2r*hr - y2i*hi, u2i = y2r*hi + y2i*hr;
    hr = __bfloat162float(h3.x); hi = __bfloat162float(h3.y);
    const float u3r = y3r*hr - y3i*hi, u3i = y3r*hi + y3i*hr;
    // inv radix-4 head
    const float e0r = u0r + u2r, e0i = u0i + u2i;
    const float e1r = u0r - u2r, e1i = u0i - u2i;
    const float f0r = u1r + u3r, f0i = u1i + u3i;
    const float f1r = u1r - u3r, f1i = u1i - u3i;
    z[IDX(i0    )] = make_float2(e0r + f0r, e0i + f0i);
    z[IDX(i0 + 1)] = make_float2(e1r - f1i, e1i + f1r);
    z[IDX(i0 + 2)] = make_float2(e0r - f0r, e0i - f0i);
    z[IDX(i0 + 3)] = make_float2(e1r + f1i, e1i - f1r);
  }
  __syncthreads();
}

template<int NT>
__device__ __forceinline__ void inv_pairs(float2* z, int tid)
{
  #pragma unroll
  for (int lq = 2; lq <= 10; lq += 4) {      // fused pair: stage lq then lq+2
    const int q = 1 << lq;
    const int Q = q << 2;
    const float stw1 = TWO_PI / (float)(q << 2);
    const float stw2 = TWO_PI / (float)(Q << 2);
    for (int g = tid; g < NFFT / 16; g += NT) {
      const int j    = g & (q - 1);
      const int base = ((g >> lq) << (lq + 4)) + j;
      float xr[4][4], xi4[4][4];
      #pragma unroll
      for (int k = 0; k < 4; ++k)
        #pragma unroll
        for (int m = 0; m < 4; ++m) {
          const float2 v = z[IDX(base + m * q + k * Q)];
          xr[k][m] = v.x; xi4[k][m] = v.y;
        }
      {                                       // layer 1: stage lq, j1 = j
        float c1, s1, c2, s2, c3, s3;
        rot3(stw1 * (float)j, c1, s1, c2, s2, c3, s3);
        #pragma unroll
        for (int k = 0; k < 4; ++k) {
          float u0r = xr[k][0], u0i = xi4[k][0];
          float u1r = xr[k][1]*c1 - xi4[k][1]*s1, u1i = xr[k][1]*s1 + xi4[k][1]*c1;
          float u2r = xr[k][2]*c2 - xi4[k][2]*s2, u2i = xr[k][2]*s2 + xi4[k][2]*c2;
          float u3r = xr[k][3]*c3 - xi4[k][3]*s3, u3i = xr[k][3]*s3 + xi4[k][3]*c3;
          float e0r = u0r + u2r, e0i = u0i + u2i;
          float e1r = u0r - u2r, e1i = u0i - u2i;
          float f0r = u1r + u3r, f0i = u1i + u3i;
          float f1r = u1r - u3r, f1i = u1i - u3i;
          xr[k][0] = e0r + f0r; xi4[k][0] = e0i + f0i;
          xr[k][1] = e1r - f1i; xi4[k][1] = e1i + f1r;
          xr[k][2] = e0r - f0r; xi4[k][2] = e0i - f0i;
          xr[k][3] = e1r + f1i; xi4[k][3] = e1i - f1r;
        }
      }
      #pragma unroll
      for (int m = 0; m < 4; ++m) {           // layer 2: stage lq+2
        float c1, s1, c2, s2, c3, s3;
        rot3(stw2 * (float)(j + m * q), c1, s1, c2, s2, c3, s3);
        float u0r = xr[0][m], u0i = xi4[0][m];
        float u1r = xr[1][m]*c1 - xi4[1][m]*s1, u1i = xr[1][m]*s1 + xi4[1][m]*c1;
        float u2r = xr[2][m]*c2 - xi4[2][m]*s2, u2i = xr[2][m]*s2 + xi4[2][m]*c2;
        float u3r = xr[3][m]*c3 - xi4[3][m]*s3, u3i = xr[3][m]*s3 + xi4[3][m]*c3;
        float e0r = u0r + u2r, e0i = u0i + u2i;
        float e1r = u0r - u2r, e1i = u0i - u2i;
        float f0r = u1r + u3r, f0i = u1i + u3i;
        float f1r = u1r - u3r, f1i = u1i - u3i;
        const int i0 = base + m * q;
        z[IDX(i0        )] = make_float2(e0r + f0r, e0i + f0i);
        z[IDX(i0 +     Q)] = make_float2(e1r - f1i, e1i + f1r);
        z[IDX(i0 + 2 * Q)] = make_float2(e0r - f0r, e0i - f0i);
        z[IDX(i0 + 3 * Q)] = make_float2(e1r + f1i, e1i - f1r);
      }
    }
    __syncthreads();
  }
}

// depthwise conv3 on a bf16 row, SAME padding (XLA cross-correlation)
__device__ __forceinline__ float conv3b(const u16* __restrict__ row, int t,
                                        float w0, float w1, float w2, float sb)
{
  float l = (t > 0)         ? bf2f(row[t - 1]) : 0.0f;
  float c = bf2f(row[t]);
  float r = (t < L_SEQ - 1) ? bf2f(row[t + 1]) : 0.0f;
  return w0 * l + w1 * c + w2 * r + sb;
}

// ===========================================================================
// Prep kernels (unchanged)
// ===========================================================================
__global__ __launch_bounds__(256)
void cast_bf16_kernel(const float* __restrict__ in, u16* __restrict__ out, int n4)
{
  int i = blockIdx.x * 256 + threadIdx.x;
  if (i < n4) {
    float4 v = ((const float4*)in)[i];
    U16x4 w; w.x = f2bf(v.x); w.y = f2bf(v.y); w.z = f2bf(v.z); w.w = f2bf(v.w);
    ((U16x4*)out)[i] = w;
  }
}

__global__ __launch_bounds__(256)
void transpose_cast_kernel(const float* __restrict__ in, u16* __restrict__ out,
                           int K, int N)   // in [K][N] fp32 -> out [N][K] bf16
{
  __shared__ u16 tile[32][33];
  const int n0 = blockIdx.x * 32, k0 = blockIdx.y * 32;
  const int tx = threadIdx.x & 31, ty = threadIdx.x >> 5;
  #pragma unroll
  for (int i = 0; i < 32; i += 8)
    tile[ty + i][tx] = f2bf(in[(size_t)(k0 + ty + i) * N + n0 + tx]);
  __syncthreads();
  #pragma unroll
  for (int i = 0; i < 32; i += 8)
    out[(size_t)(n0 + ty + i) * K + k0 + tx] = tile[tx][ty + i];
}

__global__ __launch_bounds__(256)
void transpose_v_kernel(const u16* __restrict__ vb, u16* __restrict__ out)
{
  __shared__ u16 t2[64][65];
  const int m0 = blockIdx.x * 64, f0 = blockIdx.y * 64;
  const int tx = threadIdx.x & 63, ty = threadIdx.x >> 6;
  #pragma unroll
  for (int i = 0; i < 64; i += 4)
    t2[ty + i][tx] = vb[(size_t)(f0 + ty + i) * (2 * NFFT) + m0 + tx];
  __syncthreads();
  #pragma unroll
  for (int i = 0; i < 64; i += 4)
    out[(size_t)(m0 + ty + i) * F_DIM + f0 + tx] = t2[tx][ty + i];
}

// ===========================================================================
// MFMA GEMM (unchanged, verified)
// ===========================================================================
template<int N_DIM, int K_DIM, int WMODE>
__global__ __launch_bounds__(256)
void mfma_gemm_kernel(const u16* __restrict__ A, const u16* __restrict__ B,
                      const float* __restrict__ bias, void* __restrict__ Cv)
{
  constexpr int BK = 64;
  __shared__ u16 As[128 * BK];
  __shared__ u16 Bs[128 * BK];
  const int tid  = threadIdx.x;
  const int lane = tid & 63;
  const int wid  = tid >> 6;
  const int m0 = blockIdx.x * 128;
  const int n0 = blockIdx.y * 128;

  const u16* aPtr[4]; const u16* bPtr[4];
  #pragma unroll
  for (int i = 0; i < 4; ++i) {
    const int g = tid + (i << 8);
    aPtr[i] = A + (size_t)(m0 + (g >> 3)) * K_DIM + ((g & 7) << 3);
    bPtr[i] = B + (size_t)(n0 + (g >> 3)) * K_DIM + ((g & 7) << 3);
  }

  const int wm = (wid & 1) << 6;
  const int wn = (wid >> 1) << 6;
  int aoff[4], boff[4];
  #pragma unroll
  for (int f = 0; f < 4; ++f) {
    aoff[f] = (wm + f * 16 + (lane & 15)) * BK + ((lane >> 4) << 3);
    boff[f] = (wn + f * 16 + (lane & 15)) * BK + ((lane >> 4) << 3);
  }

  f32x4 acc[4][4];
  #pragma unroll
  for (int i = 0; i < 4; ++i)
    #pragma unroll
    for (int j = 0; j < 4; ++j)
      acc[i][j] = (f32x4){0.f, 0.f, 0.f, 0.f};

  for (int k0 = 0; k0 < K_DIM; k0 += BK) {
    #pragma unroll
    for (int i = 0; i < 4; ++i) {
      __builtin_amdgcn_global_load_lds(
          (const __attribute__((address_space(1))) void*)aPtr[i],
          (__attribute__((address_space(3))) void*)&As[(((wid << 6) + (i << 8)) << 3)],
          16, 0, 0);
      aPtr[i] += BK;
    }
    #pragma unroll
    for (int i = 0; i < 4; ++i) {
      __builtin_amdgcn_global_load_lds(
          (const __attribute__((address_space(1))) void*)bPtr[i],
          (__attribute__((address_space(3))) void*)&Bs[(((wid << 6) + (i << 8)) << 3)],
          16, 0, 0);
      bPtr[i] += BK;
    }
    __syncthreads();
    #pragma unroll
    for (int kk = 0; kk < 2; ++kk) {
      bf16x8 af[4], bg[4];
      #pragma unroll
      for (int f = 0; f < 4; ++f) af[f] = *(const bf16x8*)&As[aoff[f] + kk * 32];
      #pragma unroll
      for (int f = 0; f < 4; ++f) bg[f] = *(const bf16x8*)&Bs[boff[f] + kk * 32];
      #pragma unroll
      for (int fm = 0; fm < 4; ++fm)
        #pragma unroll
        for (int fn = 0; fn < 4; ++fn)
          acc[fm][fn] = __builtin_amdgcn_mfma_f32_16x16x32_bf16(
              af[fm], bg[fn], acc[fm][fn], 0, 0, 0);
    }
    __syncthreads();
  }

  if (WMODE == 0) {
    u16* C = (u16*)Cv;
    const int b = m0 >> 13;
    const int tbase = (m0 & (L_SEQ - 1)) + wm + ((lane >> 4) << 2);
    #pragma unroll
    for (int fn = 0; fn < 4; ++fn) {
      const int n = n0 + wn + fn * 16 + (lane & 15);
      const float bv = bias[n];
      u16* row = C + ((size_t)b * N_DIM + n) * L_SEQ;
      #pragma unroll
      for (int fm = 0; fm < 4; ++fm) {
        f32x4 v = acc[fm][fn];
        U16x4 w;
        w.x = f2bf(v[0] + bv); w.y = f2bf(v[1] + bv);
        w.z = f2bf(v[2] + bv); w.w = f2bf(v[3] + bv);
        *(U16x4*)&row[tbase + fm * 16] = w;
      }
    }
  } else {
    float* C = (float*)Cv;
    #pragma unroll
    for (int fn = 0; fn < 4; ++fn) {
      const int n = n0 + wn + fn * 16 + (lane & 15);
      const float bv = bias[n];
      #pragma unroll
      for (int fm = 0; fm < 4; ++fm) {
        const int mb = m0 + wm + fm * 16 + ((lane >> 4) << 2);
        f32x4 v = acc[fm][fn];
        #pragma unroll
        for (int r = 0; r < 4; ++r)
          C[(size_t)(mb + r) * N_DIM + n] = v[r] + bv;
      }
    }
  }
}

// ===========================================================================
// Kernel A: filter MLP (unchanged, verified)
// ===========================================================================
__global__ __launch_bounds__(256)
void filter_gen_kernel(const float* __restrict__ w1, const float* __restrict__ b1,
                       const float* __restrict__ w2, const float* __restrict__ b2,
                       const float* __restrict__ decay, float* __restrict__ h_t)
{
  __shared__ float hid[64][65];
  const int tid  = threadIdx.x;
  const int tau0 = blockIdx.x * 64;
  const int c0   = blockIdx.y * 256;
  {
    const int r = tid & 63;
    const int tb = tid >> 6;
    const float w1v0 = w1[r];
    const float b1v = b1[r];
    float w1c[4], w1s[4];
    #pragma unroll
    for (int p = 0; p < 4; ++p) { w1c[p] = w1[(1 + p) * 64 + r]; w1s[p] = w1[(5 + p) * 64 + r]; }
    #pragma unroll
    for (int i = 0; i < 16; ++i) {
      const int tl = tb + i * 4;
      const int tau = tau0 + tl;
      const float off = (tau < L_SEQ) ? (float)tau : (float)(tau - NFFT);
      float acc = b1v + off * (1.0f / 8192.0f) * w1v0;
      #pragma unroll
      for (int p = 0; p < 4; ++p) {
        const double period = 4.0 + (8188.0 * p) / 3.0;
        const float freq = (float)(6.283185307179586476925287 / period);
        float sp, cp;
        sincosf(off * freq, &sp, &cp);
        acc += cp * w1c[p] + sp * w1s[p];
      }
      hid[r][tl] = sinf(acc);
    }
  }
  __syncthreads();

  const int tx = tid & 63;
  const int ty = tid >> 6;
  const int taug = tau0 + tx;
  const float mt = (taug < L_SEQ) ? (float)taug * (1.0f / 8191.0f)
                                  : (float)(NFFT - 1 - taug) * (1.0f / 8191.0f);
  const int cbase = c0 + ty * 64;
  for (int cb = 0; cb < 8; ++cb) {
    const int c8 = cbase + cb * 8;
    float acc[8];
    #pragma unroll
    for (int jj = 0; jj < 8; ++jj) acc[jj] = b2[c8 + jj];
    for (int rr = 0; rr < 64; ++rr) {
      const float hv = hid[rr][tx];
      const float4 wa = *(const float4*)&w2[rr * 1536 + c8];
      const float4 wb = *(const float4*)&w2[rr * 1536 + c8 + 4];
      acc[0] += hv * wa.x; acc[1] += hv * wa.y; acc[2] += hv * wa.z; acc[3] += hv * wa.w;
      acc[4] += hv * wb.x; acc[5] += hv * wb.y; acc[6] += hv * wb.z; acc[7] += hv * wb.w;
    }
    #pragma unroll
    for (int jj = 0; jj < 8; ++jj) {
      const int c = c8 + jj;
      const float dec = __expf(-mt * fabsf(decay[c]));
      h_t[(size_t)c * NFFT + taug] = acc[jj] * dec;
    }
  }
}

// ===========================================================================
// Kernel B: filter spectra IN PLACE (fp32 row -> bf16x2 spectrum; bias folded)
// stage 1 sources real input straight from global; final quad fused with the
// bf16x2 output store (16B per quad).
// ===========================================================================
__global__ __launch_bounds__(NT_FFT, 4)
void filter_fft_kernel(float* __restrict__ hH, const float* __restrict__ bias)
{
  __shared__ float2 z[NZ];
  const int row = blockIdx.x;
  const int tid = threadIdx.x;
  float* h = hH + (size_t)row * NFFT;

  // stage 1 (lq=12,10) on real global input (imag == 0 exactly)
  const float stw1 = -TWO_PI / 16384.0f;
  for (int g = tid; g < 1024; g += NT_FFT) {
    float x[4][4];
    #pragma unroll
    for (int k = 0; k < 4; ++k)
      #pragma unroll
      for (int m = 0; m < 4; ++m)
        x[k][m] = h[g + (m << 10) + (k << 12)];
    float yr[4][4], yi4[4][4];
    #pragma unroll
    for (int m = 0; m < 4; ++m) {
      const float t0 = x[0][m] + x[2][m];
      const float t1 = x[0][m] - x[2][m];
      const float t2 = x[1][m] + x[3][m];
      const float t3 = x[1][m] - x[3][m];
      float c1, s1, c2, s2, c3, s3;
      rot3(stw1 * (float)(g + (m << 10)), c1, s1, c2, s2, c3, s3);
      yr[0][m] = t0 + t2;           yi4[0][m] = 0.0f;
      yr[1][m] = t1*c1 + t3*s1;     yi4[1][m] = t1*s1 - t3*c1;   // y1=(t1,-t3)
      yr[2][m] = (t0 - t2)*c2;      yi4[2][m] = (t0 - t2)*s2;
      yr[3][m] = t1*c3 - t3*s3;     yi4[3][m] = t1*s3 + t3*c3;   // y3=(t1, t3)
    }
    stage1_layer2_store(z, g, yr, yi4);
  }
  __syncthreads();
  fwd_mid_pairs<NT_FFT>(z, tid);

  const float bo = bias[row];
  const float s = 1.0f / (float)NFFT;
  __hip_bfloat162* out2 = (__hip_bfloat162*)h;
  for (int b = tid; b < NFFT / 4; b += NT_FFT) {
    const int i0 = b << 2;
    const float2 a0 = z[IDX(i0)],     a1 = z[IDX(i0 + 1)];
    const float2 a2 = z[IDX(i0 + 2)], a3 = z[IDX(i0 + 3)];
    const float t0r = a0.x + a2.x, t0i = a0.y + a2.y;
    const float t1r = a0.x - a2.x, t1i = a0.y - a2.y;
    const float t2r = a1.x + a3.x, t2i = a1.y + a3.y;
    const float t3r = a1.x - a3.x, t3i = a1.y - a3.y;
    union { float4 f4; __hip_bfloat162 hh[4]; } o;
    o.hh[0].x = __float2bfloat16((t0r + t2r + bo) * s);
    o.hh[0].y = __float2bfloat16((t0i + t2i) * s);
    o.hh[1].x = __float2bfloat16((t1r + t3i + bo) * s);
    o.hh[1].y = __float2bfloat16((t1i - t3r) * s);
    o.hh[2].x = __float2bfloat16((t0r - t2r + bo) * s);
    o.hh[2].y = __float2bfloat16((t0i - t2i) * s);
    o.hh[3].x = __float2bfloat16((t1r - t3i + bo) * s);
    o.hh[3].y = __float2bfloat16((t1i + t3r) * s);
    *(float4*)&out2[i0] = o.f4;
  }
}

// ===========================================================================
// Kernel C: fused shortconv + 2x (FFT conv + gate); bf16 in, bf16 v rows out.
// Interleaved-complex LDS (b64), stage-1 zero-upper-half fusion (o=0 sources
// conv3 from global; o=1 from gated LDS), fwd-final+spec_mul+inv-head fused.
// 1024 threads, launch_bounds(1024,4): 4 waves/SIMD resident, 128-VGPR budget.
// ===========================================================================
__global__ __launch_bounds__(NT_FFT, 4)
void fftconv_kernel(const u16* __restrict__ up, float* __restrict__ hH,
                    const float* __restrict__ sw, const float* __restrict__ sb)
{
  __shared__ float2 z[NZ];
  const int f = blockIdx.x;
  const int tid = threadIdx.x;
  float* rowf = hH + (size_t)f * NFFT;            // o=0 spectra; later v01 out
  float* row1 = hH + (size_t)(F_DIM + f) * NFFT;  // o=1 spectra

  const u16* u0 = up + (size_t)(0 * C_IN + f) * L_SEQ;
  const u16* u1 = up + (size_t)(1 * C_IN + f) * L_SEQ;
  const float vw0 = sw[f], vw1 = sw[C_IN + f], vw2 = sw[2 * C_IN + f];
  const float vb = sb[f];

  // ===== o = 0 =====
  // stage 1 fused with conv3 input from global (upper half exactly zero)
  for (int g = tid; g < 1024; g += NT_FFT) {
    float xr[2][4], xi[2][4];
    #pragma unroll
    for (int k = 0; k < 2; ++k)
      #pragma unroll
      for (int m = 0; m < 4; ++m) {
        const int t = g + (m << 10) + (k << 12);
        xr[k][m] = conv3b(u0, t, vw0, vw1, vw2, vb);
        xi[k][m] = conv3b(u1, t, vw0, vw1, vw2, vb);
      }
    stage1_tail_zero_hi(z, g, xr, xi);
  }
  __syncthreads();
  fwd_mid_pairs<NT_FFT>(z, tid);
  fwd_final_spec_inv_head<NT_FFT>(z, (const __hip_bfloat162*)rowf, tid);
  inv_pairs<NT_FFT>(z, tid);

  // gate o=0 result; this doubles as the o=1 input (upper half ignored by
  // the zero-hi stage 1, so no zero-fill pass is needed)
  const int c0g = F_DIM + f;
  const u16* x0 = up + (size_t)(0 * C_IN + c0g) * L_SEQ;
  const u16* x1 = up + (size_t)(1 * C_IN + c0g) * L_SEQ;
  const float xw0 = sw[c0g], xw1 = sw[C_IN + c0g], xw2 = sw[2 * C_IN + c0g];
  const float xb = sb[c0g];
  for (int t = tid; t < L_SEQ; t += NT_FFT) {
    const int ip = IDX(t);
    float2 v = z[ip];
    v.x *= conv3b(x0, t, xw0, xw1, xw2, xb);
    v.y *= conv3b(x1, t, xw0, xw1, xw2, xb);
    z[ip] = v;
  }
  __syncthreads();

  // ===== o = 1 =====
  for (int g = tid; g < 1024; g += NT_FFT) {
    float xr[2][4], xi[2][4];
    #pragma unroll
    for (int k = 0; k < 2; ++k)
      #pragma unroll
      for (int m = 0; m < 4; ++m) {
        const float2 v = z[IDX(g + (m << 10) + (k << 12))];
        xr[k][m] = v.x; xi[k][m] = v.y;
      }
    stage1_tail_zero_hi(z, g, xr, xi);
  }
  __syncthreads();
  fwd_mid_pairs<NT_FFT>(z, tid);
  fwd_final_spec_inv_head<NT_FFT>(z, (const __hip_bfloat162*)row1, tid);
  inv_pairs<NT_FFT>(z, tid);

  // final gate + bf16 output (row f spectra consumed; reuse as v01 rows)
  const int c1g = 2 * F_DIM + f;
  const u16* y0 = up + (size_t)(0 * C_IN + c1g) * L_SEQ;
  const u16* y1 = up + (size_t)(1 * C_IN + c1g) * L_SEQ;
  const float yw0 = sw[c1g], yw1 = sw[C_IN + c1g], yw2 = sw[2 * C_IN + c1g];
  const float yb = sb[c1g];
  u16* v01 = (u16*)rowf;
  for (int t = tid; t < L_SEQ; t += NT_FFT) {
    const int ip = IDX(t);
    const float2 v = z[ip];
    v01[t]         = f2bf(v.x * conv3b(y0, t, yw0, yw1, yw2, yb));
    v01[L_SEQ + t] = f2bf(v.y * conv3b(y1, t, yw0, yw1, yw2, yb));
  }
}

// ===========================================================================
extern "C" void kernel_launch(void* const* d_in, const int* in_sizes, int n_in,
                              void* d_out, int out_size, void* d_ws, size_t ws_size,
                              hipStream_t stream)
{
  (void)in_sizes; (void)n_in; (void)out_size; (void)ws_size;
  const float* u     = (const float*)d_in[0];
  const float* fw1   = (const float*)d_in[1];
  const float* fb1   = (const float*)d_in[2];
  const float* fw2   = (const float*)d_in[3];
  const float* fb2   = (const float*)d_in[4];
  const float* decay = (const float*)d_in[5];
  const float* bias  = (const float*)d_in[6];
  const float* ipw   = (const float*)d_in[7];
  const float* ipb   = (const float*)d_in[8];
  const float* sw    = (const float*)d_in[9];
  const float* sb    = (const float*)d_in[10];
  const float* ow    = (const float*)d_in[11];
  const float* ob    = (const float*)d_in[12];
  float* out = (float*)d_out;

  char* ws = (char*)d_ws;
  u16*   up_t  = (u16*)(ws);                                // 75,497,472 B
  float* hH    = (float*)(ws + 75497472);                   // 100,663,296 B
  u16*   u_bf  = (u16*)(ws + 176160768);                    // 25,165,824 B
  u16*   ipw_t = (u16*)(ws + 201326592);                    // 3,538,944 B
  u16*   ow_t  = (u16*)(ws + 204865536);                    // 1,179,648 B
  u16*   vt_t  = (u16*)(ws + 206045184);                    // 25,165,824 B

  cast_bf16_kernel<<<dim3(12288), 256, 0, stream>>>(u, u_bf, (2 * L_SEQ * D_DIM) / 4);
  transpose_cast_kernel<<<dim3(C_IN / 32, D_DIM / 32), 256, 0, stream>>>(ipw, ipw_t, D_DIM, C_IN);
  transpose_cast_kernel<<<dim3(D_DIM / 32, F_DIM / 32), 256, 0, stream>>>(ow, ow_t, F_DIM, D_DIM);

  filter_gen_kernel<<<dim3(NFFT / 64, 1536 / 256), 256, 0, stream>>>(fw1, fb1, fw2, fb2, decay, hH);
  filter_fft_kernel<<<dim3(NORD * F_DIM), NT_FFT, 0, stream>>>(hH, bias);

  mfma_gemm_kernel<C_IN, D_DIM, 0><<<dim3(128, C_IN / 128), 256, 0, stream>>>(u_bf, ipw_t, ipb, up_t);
  fftconv_kernel<<<dim3(F_DIM), NT_FFT, 0, stream>>>(up_t, hH, sw, sb);
  transpose_v_kernel<<<dim3(NFFT / 64, F_DIM / 64), 256, 0, stream>>>((const u16*)hH, vt_t);
  mfma_gemm_kernel<D_DIM, F_DIM, 1><<<dim3(128, D_DIM / 128), 256, 0, stream>>>(vt_t, ow_t, ob, out);
}

// Round 7
// 687.078 us; speedup vs baseline: 1.5490x; 1.5490x over previous
//
#include <hip/hip_runtime.h>
#include <hip/hip_bf16.h>
#include <math.h>

#define L_SEQ 8192
#define NFFT  16384
#define NPAD  16896   // NFFT + NFFT/32 padding (floats per array)
#define F_DIM 768
#define D_DIM 768
#define C_IN  2304    // INNER = F*(ORDER+1)
#define NORD  2
#define NT    512
#define TWO_PI 6.2831853071795864769f

typedef unsigned short u16;
typedef __attribute__((ext_vector_type(8))) short bf16x8;
typedef __attribute__((ext_vector_type(4))) float f32x4;
struct __align__(8) U16x4 { u16 x, y, z, w; };

__device__ __forceinline__ float bf2f(u16 v) {
  unsigned u = ((unsigned)v) << 16; float f; __builtin_memcpy(&f, &u, 4); return f;
}
__device__ __forceinline__ u16 f2bf(float f) {
  __hip_bfloat16 h = __float2bfloat16(f); u16 r; __builtin_memcpy(&r, &h, 2); return r;
}

// LDS pad: bank(i) shifts by 1 every 32 floats -> all FFT strides <=2-way (free).
// NOTE: pad stride 1 breaks 8/16B alignment classes -> LDS access must stay b32.
__device__ __forceinline__ int PAD(int i) { return i + (i >> 5); }

__device__ __forceinline__ void rot3(float ang, float& c1, float& s1,
                                     float& c2, float& s2, float& c3, float& s3)
{
  __sincosf(ang, &s1, &c1);
  c2 = c1 * c1 - s1 * s1; s2 = 2.0f * c1 * s1;
  c3 = c1 * c2 - s1 * s2; s3 = c1 * s2 + s1 * c2;
}

// depthwise conv3 on a bf16 row, SAME padding (XLA cross-correlation)
__device__ __forceinline__ float conv3b(const u16* __restrict__ row, int t,
                                        float w0, float w1, float w2, float sb)
{
  float l = (t > 0)         ? bf2f(row[t - 1]) : 0.0f;
  float c = bf2f(row[t]);
  float r = (t < L_SEQ - 1) ? bf2f(row[t + 1]) : 0.0f;
  return w0 * l + w1 * c + w2 * r + sb;
}

// ===========================================================================
// Radix-4 FFT, N = 16384 = 4^7, PLANAR zr/zi in LDS (b32, 2-way-free PAD).
// fwd: DIF pair (12,10) fused with input, pairs (8,6)(4,2), final quad fused
//      with spectrum-mul + inv head (scalar b32, same-quad registers).
// inv: head (fused above), pairs (2,4)(6,8), last pair (10,12) fused with
//      gate + output (only t<8192 written).  All stage algebra verbatim from
//      the verified round-0/round-2 kernels.
// ===========================================================================

// layer-2 (stage 10) + planar stores of the first fwd pair. g in [0,1024).
__device__ __forceinline__ void s1_l2_store(float* zr, float* zi, int g,
    const float yr[4][4], const float yi4[4][4])
{
  const float stw2 = -TWO_PI / 4096.0f;
  float c1, s1, c2, s2, c3, s3;
  rot3(stw2 * (float)g, c1, s1, c2, s2, c3, s3);
  #pragma unroll
  for (int k = 0; k < 4; ++k) {
    float t0r = yr[k][0] + yr[k][2], t0i = yi4[k][0] + yi4[k][2];
    float t1r = yr[k][0] - yr[k][2], t1i = yi4[k][0] - yi4[k][2];
    float t2r = yr[k][1] + yr[k][3], t2i = yi4[k][1] + yi4[k][3];
    float t3r = yr[k][1] - yr[k][3], t3i = yi4[k][1] - yi4[k][3];
    float o0r = t0r + t2r, o0i = t0i + t2i;
    float o1r = t1r + t3i, o1i = t1i - t3r;
    float o2r = t0r - t2r, o2i = t0i - t2i;
    float o3r = t1r - t3i, o3i = t1i + t3r;
    const int i0 = g + (k << 12);
    zr[PAD(i0       )] = o0r;               zi[PAD(i0       )] = o0i;
    zr[PAD(i0 + 1024)] = o1r*c1 - o1i*s1;   zi[PAD(i0 + 1024)] = o1r*s1 + o1i*c1;
    zr[PAD(i0 + 2048)] = o2r*c2 - o2i*s2;   zi[PAD(i0 + 2048)] = o2r*s2 + o2i*c2;
    zr[PAD(i0 + 3072)] = o3r*c3 - o3i*s3;   zi[PAD(i0 + 3072)] = o3r*s3 + o3i*c3;
  }
}

// stage-1 layer-1 with k=2,3 inputs == 0 (zero-padded upper half).
__device__ __forceinline__ void s1_zero_hi(float* zr, float* zi, int g,
    const float xr[2][4], const float xi[2][4])
{
  const float stw1 = -TWO_PI / 16384.0f;
  float yr[4][4], yi4[4][4];
  #pragma unroll
  for (int m = 0; m < 4; ++m) {
    const float x0r = xr[0][m], x0i = xi[0][m];
    const float x1r = xr[1][m], x1i = xi[1][m];
    const float y0r = x0r + x1r, y0i = x0i + x1i;
    const float y1r = x0r + x1i, y1i = x0i - x1r;
    const float y2r = x0r - x1r, y2i = x0i - x1i;
    const float y3r = x0r - x1i, y3i = x0i + x1r;
    float c1, s1, c2, s2, c3, s3;
    rot3(stw1 * (float)(g + (m << 10)), c1, s1, c2, s2, c3, s3);
    yr[0][m] = y0r;               yi4[0][m] = y0i;
    yr[1][m] = y1r*c1 - y1i*s1;   yi4[1][m] = y1r*s1 + y1i*c1;
    yr[2][m] = y2r*c2 - y2i*s2;   yi4[2][m] = y2r*s2 + y2i*c2;
    yr[3][m] = y3r*c3 - y3i*s3;   yi4[3][m] = y3r*s3 + y3i*c3;
  }
  s1_l2_store(zr, zi, g, yr, yi4);
}

// fwd middle pairs (8,6)(4,2) — planar body verbatim from round 0
__device__ __forceinline__ void fwd_mid_pairs(float* zr, float* zi, int tid)
{
  #pragma unroll
  for (int lq = 8; lq >= 4; lq -= 4) {
    const int q  = 1 << lq;
    const int q4 = q >> 2;
    const float stw1 = -TWO_PI / (float)(q << 2);
    const float stw2 = -TWO_PI / (float)q;
    for (int g = tid; g < NFFT / 16; g += NT) {
      const int j    = g & (q4 - 1);
      const int base = ((g >> (lq - 2)) << (lq + 2)) + j;
      float xr[4][4], xi4[4][4];
      #pragma unroll
      for (int k = 0; k < 4; ++k)
        #pragma unroll
        for (int m = 0; m < 4; ++m) {
          const int idx = PAD(base + m * q4 + k * q);
          xr[k][m] = zr[idx]; xi4[k][m] = zi[idx];
        }
      #pragma unroll
      for (int m = 0; m < 4; ++m) {
        float t0r = xr[0][m] + xr[2][m], t0i = xi4[0][m] + xi4[2][m];
        float t1r = xr[0][m] - xr[2][m], t1i = xi4[0][m] - xi4[2][m];
        float t2r = xr[1][m] + xr[3][m], t2i = xi4[1][m] + xi4[3][m];
        float t3r = xr[1][m] - xr[3][m], t3i = xi4[1][m] - xi4[3][m];
        float y0r = t0r + t2r, y0i = t0i + t2i;
        float y1r = t1r + t3i, y1i = t1i - t3r;
        float y2r = t0r - t2r, y2i = t0i - t2i;
        float y3r = t1r - t3i, y3i = t1i + t3r;
        float c1, s1, c2, s2, c3, s3;
        rot3(stw1 * (float)(j + m * q4), c1, s1, c2, s2, c3, s3);
        xr[0][m] = y0r;                xi4[0][m] = y0i;
        xr[1][m] = y1r * c1 - y1i * s1; xi4[1][m] = y1r * s1 + y1i * c1;
        xr[2][m] = y2r * c2 - y2i * s2; xi4[2][m] = y2r * s2 + y2i * c2;
        xr[3][m] = y3r * c3 - y3i * s3; xi4[3][m] = y3r * s3 + y3i * c3;
      }
      float c1, s1, c2, s2, c3, s3;
      rot3(stw2 * (float)j, c1, s1, c2, s2, c3, s3);
      #pragma unroll
      for (int k = 0; k < 4; ++k) {
        float t0r = xr[k][0] + xr[k][2], t0i = xi4[k][0] + xi4[k][2];
        float t1r = xr[k][0] - xr[k][2], t1i = xi4[k][0] - xi4[k][2];
        float t2r = xr[k][1] + xr[k][3], t2i = xi4[k][1] + xi4[k][3];
        float t3r = xr[k][1] - xr[k][3], t3i = xi4[k][1] - xi4[k][3];
        float y0r = t0r + t2r, y0i = t0i + t2i;
        float y1r = t1r + t3i, y1i = t1i - t3r;
        float y2r = t0r - t2r, y2i = t0i - t2i;
        float y3r = t1r - t3i, y3i = t1i + t3r;
        const int i0 = base + k * q;
        zr[PAD(i0         )] = y0r;            zi[PAD(i0         )] = y0i;
        zr[PAD(i0 +     q4)] = y1r*c1 - y1i*s1; zi[PAD(i0 +     q4)] = y1r*s1 + y1i*c1;
        zr[PAD(i0 + 2 * q4)] = y2r*c2 - y2i*s2; zi[PAD(i0 + 2 * q4)] = y2r*s2 + y2i*c2;
        zr[PAD(i0 + 3 * q4)] = y3r*c3 - y3i*s3; zi[PAD(i0 + 3 * q4)] = y3r*s3 + y3i*c3;
      }
    }
    __syncthreads();
  }
}

// fwd final radix-4 + spectrum multiply + inv head fused in registers.
// Scalar b32 LDS access (PAD breaks 16B alignment; b128 here is UB).
__device__ __forceinline__ void fused_final_spec_head(float* zr, float* zi,
    const __hip_bfloat162* __restrict__ H, int tid)
{
  for (int b = tid; b < NFFT / 4; b += NT) {
    const int i0 = b << 2;
    const int p  = PAD(i0);                  // quad never crosses pad stripe
    const float a0r = zr[p],     a0i = zi[p];
    const float a1r = zr[p + 1], a1i = zi[p + 1];
    const float a2r = zr[p + 2], a2i = zi[p + 2];
    const float a3r = zr[p + 3], a3i = zi[p + 3];
    float t0r = a0r + a2r, t0i = a0i + a2i;
    float t1r = a0r - a2r, t1i = a0i - a2i;
    float t2r = a1r + a3r, t2i = a1i + a3i;
    float t3r = a1r - a3r, t3i = a1i - a3i;
    float y0r = t0r + t2r, y0i = t0i + t2i;
    float y1r = t1r + t3i, y1i = t1i - t3r;
    float y2r = t0r - t2r, y2i = t0i - t2i;
    float y3r = t1r - t3i, y3i = t1i + t3r;
    // spectrum multiply: 4 bf16x2 in one 16B global load (aligned)
    const float4 hq = *(const float4*)&H[i0];
    __hip_bfloat162 h0, h1, h2, h3;
    __builtin_memcpy(&h0, &hq.x, 4); __builtin_memcpy(&h1, &hq.y, 4);
    __builtin_memcpy(&h2, &hq.z, 4); __builtin_memcpy(&h3, &hq.w, 4);
    float hr, hi;
    hr = __bfloat162float(h0.x); hi = __bfloat162float(h0.y);
    const float u0r = y0r*hr - y0i*hi, u0i = y0r*hi + y0i*hr;
    hr = __bfloat162float(h1.x); hi = __bfloat162float(h1.y);
    const float u1r = y1r*hr - y1i*hi, u1i = y1r*hi + y1i*hr;
    hr = __bfloat162float(h2.x); hi = __bfloat162float(h2.y);
    const float u2r = y2r*hr - y2i*hi, u2i = y2r*hi + y2i*hr;
    hr = __bfloat162float(h3.x); hi = __bfloat162float(h3.y);
    const float u3r = y3r*hr - y3i*hi, u3i = y3r*hi + y3i*hr;
    // inv radix-4 head
    const float e0r = u0r + u2r, e0i = u0i + u2i;
    const float e1r = u0r - u2r, e1i = u0i - u2i;
    const float f0r = u1r + u3r, f0i = u1i + u3i;
    const float f1r = u1r - u3r, f1i = u1i - u3i;
    zr[p]     = e0r + f0r; zi[p]     = e0i + f0i;
    zr[p + 1] = e1r - f1i; zi[p + 1] = e1i + f1r;
    zr[p + 2] = e0r - f0r; zi[p + 2] = e0i - f0i;
    zr[p + 3] = e1r + f1i; zi[p + 3] = e1i - f1r;
  }
  __syncthreads();
}

// inv middle pairs (2,4)(6,8) — planar body verbatim from round 0
__device__ __forceinline__ void inv_mid_pairs(float* zr, float* zi, int tid)
{
  #pragma unroll
  for (int lq = 2; lq <= 6; lq += 4) {
    const int q = 1 << lq;
    const int Q = q << 2;
    const float stw1 = TWO_PI / (float)(q << 2);
    const float stw2 = TWO_PI / (float)(Q << 2);
    for (int g = tid; g < NFFT / 16; g += NT) {
      const int j    = g & (q - 1);
      const int base = ((g >> lq) << (lq + 4)) + j;
      float xr[4][4], xi4[4][4];
      #pragma unroll
      for (int k = 0; k < 4; ++k)
        #pragma unroll
        for (int m = 0; m < 4; ++m) {
          const int idx = PAD(base + m * q + k * Q);
          xr[k][m] = zr[idx]; xi4[k][m] = zi[idx];
        }
      {
        float c1, s1, c2, s2, c3, s3;
        rot3(stw1 * (float)j, c1, s1, c2, s2, c3, s3);
        #pragma unroll
        for (int k = 0; k < 4; ++k) {
          float u0r = xr[k][0], u0i = xi4[k][0];
          float u1r = xr[k][1]*c1 - xi4[k][1]*s1, u1i = xr[k][1]*s1 + xi4[k][1]*c1;
          float u2r = xr[k][2]*c2 - xi4[k][2]*s2, u2i = xr[k][2]*s2 + xi4[k][2]*c2;
          float u3r = xr[k][3]*c3 - xi4[k][3]*s3, u3i = xr[k][3]*s3 + xi4[k][3]*c3;
          float e0r = u0r + u2r, e0i = u0i + u2i;
          float e1r = u0r - u2r, e1i = u0i - u2i;
          float f0r = u1r + u3r, f0i = u1i + u3i;
          float f1r = u1r - u3r, f1i = u1i - u3i;
          xr[k][0] = e0r + f0r; xi4[k][0] = e0i + f0i;
          xr[k][1] = e1r - f1i; xi4[k][1] = e1i + f1r;
          xr[k][2] = e0r - f0r; xi4[k][2] = e0i - f0i;
          xr[k][3] = e1r + f1i; xi4[k][3] = e1i - f1r;
        }
      }
      #pragma unroll
      for (int m = 0; m < 4; ++m) {
        float c1, s1, c2, s2, c3, s3;
        rot3(stw2 * (float)(j + m * q), c1, s1, c2, s2, c3, s3);
        float u0r = xr[0][m], u0i = xi4[0][m];
        float u1r = xr[1][m]*c1 - xi4[1][m]*s1, u1i = xr[1][m]*s1 + xi4[1][m]*c1;
        float u2r = xr[2][m]*c2 - xi4[2][m]*s2, u2i = xr[2][m]*s2 + xi4[2][m]*c2;
        float u3r = xr[3][m]*c3 - xi4[3][m]*s3, u3i = xr[3][m]*s3 + xi4[3][m]*c3;
        float e0r = u0r + u2r, e0i = u0i + u2i;
        float e1r = u0r - u2r, e1i = u0i - u2i;
        float f0r = u1r + u3r, f0i = u1i + u3i;
        float f1r = u1r - u3r, f1i = u1i - u3i;
        const int i0 = base + m * q;
        zr[PAD(i0        )] = e0r + f0r; zi[PAD(i0        )] = e0i + f0i;
        zr[PAD(i0 +     Q)] = e1r - f1i; zi[PAD(i0 +     Q)] = e1i + f1r;
        zr[PAD(i0 + 2 * Q)] = e0r - f0r; zi[PAD(i0 + 2 * Q)] = e0i - f0i;
        zr[PAD(i0 + 3 * Q)] = e1r + f1i; zi[PAD(i0 + 3 * Q)] = e1i - f1r;
      }
    }
    __syncthreads();
  }
}

// inv last pair (10,12) fused with gate; outputs only t<8192 (k=0,1).
// TO_GLOBAL=false: gated fp32 -> LDS (o=0 -> o=1 input).
// TO_GLOBAL=true : gated bf16 -> global v01 row (o=1 output).
// Per-thread position classes (mod 1024) are disjoint; reads precede writes
// within each g iteration -> no cross-thread hazard.
template<bool TO_GLOBAL>
__device__ __forceinline__ void inv_last_gate(float* zr, float* zi,
    const u16* __restrict__ gr0, const u16* __restrict__ gr1,
    float w0, float w1, float w2, float wb, u16* __restrict__ outv, int tid)
{
  const float stw1 = TWO_PI / 4096.0f;    // 2pi/(4q), q=1024
  const float stw2 = TWO_PI / 16384.0f;   // 2pi/(4Q), Q=4096
  for (int g = tid; g < 1024; g += NT) {
    float xr[4][4], xi4[4][4];
    #pragma unroll
    for (int k = 0; k < 4; ++k)
      #pragma unroll
      for (int m = 0; m < 4; ++m) {
        const int idx = PAD(g + (m << 10) + (k << 12));
        xr[k][m] = zr[idx]; xi4[k][m] = zi[idx];
      }
    {                                      // layer 1: stage 10, j1 = g
      float c1, s1, c2, s2, c3, s3;
      rot3(stw1 * (float)g, c1, s1, c2, s2, c3, s3);
      #pragma unroll
      for (int k = 0; k < 4; ++k) {
        float u0r = xr[k][0], u0i = xi4[k][0];
        float u1r = xr[k][1]*c1 - xi4[k][1]*s1, u1i = xr[k][1]*s1 + xi4[k][1]*c1;
        float u2r = xr[k][2]*c2 - xi4[k][2]*s2, u2i = xr[k][2]*s2 + xi4[k][2]*c2;
        float u3r = xr[k][3]*c3 - xi4[k][3]*s3, u3i = xr[k][3]*s3 + xi4[k][3]*c3;
        float e0r = u0r + u2r, e0i = u0i + u2i;
        float e1r = u0r - u2r, e1i = u0i - u2i;
        float f0r = u1r + u3r, f0i = u1i + u3i;
        float f1r = u1r - u3r, f1i = u1i - u3i;
        xr[k][0] = e0r + f0r; xi4[k][0] = e0i + f0i;
        xr[k][1] = e1r - f1i; xi4[k][1] = e1i + f1r;
        xr[k][2] = e0r - f0r; xi4[k][2] = e0i - f0i;
        xr[k][3] = e1r + f1i; xi4[k][3] = e1i - f1r;
      }
    }
    #pragma unroll
    for (int m = 0; m < 4; ++m) {          // layer 2: stage 12, j2 = g + m*1024
      float c1, s1, c2, s2, c3, s3;
      rot3(stw2 * (float)(g + (m << 10)), c1, s1, c2, s2, c3, s3);
      float u0r = xr[0][m], u0i = xi4[0][m];
      float u1r = xr[1][m]*c1 - xi4[1][m]*s1, u1i = xr[1][m]*s1 + xi4[1][m]*c1;
      float u2r = xr[2][m]*c2 - xi4[2][m]*s2, u2i = xr[2][m]*s2 + xi4[2][m]*c2;
      float u3r = xr[3][m]*c3 - xi4[3][m]*s3, u3i = xr[3][m]*s3 + xi4[3][m]*c3;
      float e0r = u0r + u2r, e0i = u0i + u2i;
      float e1r = u0r - u2r, e1i = u0i - u2i;
      float f0r = u1r + u3r, f0i = u1i + u3i;
      float f1r = u1r - u3r, f1i = u1i - u3i;
      const int t0 = g + (m << 10);        // k=0 output, t0 < 4096
      const int t1 = t0 + 4096;            // k=1 output, t1 < 8192
      const float o0r = e0r + f0r, o0i = e0i + f0i;
      const float o1r = e1r - f1i, o1i = e1i + f1r;
      const float a0 = conv3b(gr0, t0, w0, w1, w2, wb);
      const float b0 = conv3b(gr1, t0, w0, w1, w2, wb);
      const float a1 = conv3b(gr0, t1, w0, w1, w2, wb);
      const float b1 = conv3b(gr1, t1, w0, w1, w2, wb);
      if (TO_GLOBAL) {
        outv[t0]         = f2bf(o0r * a0);
        outv[L_SEQ + t0] = f2bf(o0i * b0);
        outv[t1]         = f2bf(o1r * a1);
        outv[L_SEQ + t1] = f2bf(o1i * b1);
      } else {
        zr[PAD(t0)] = o0r * a0;  zi[PAD(t0)] = o0i * b0;
        zr[PAD(t1)] = o1r * a1;  zi[PAD(t1)] = o1i * b1;
      }
      // k=2,3 outputs (t >= 8192) are never needed: not written.
    }
  }
  if (!TO_GLOBAL) __syncthreads();
}

// ===========================================================================
// Prep kernels (unchanged)
// ===========================================================================
__global__ __launch_bounds__(256)
void cast_bf16_kernel(const float* __restrict__ in, u16* __restrict__ out, int n4)
{
  int i = blockIdx.x * 256 + threadIdx.x;
  if (i < n4) {
    float4 v = ((const float4*)in)[i];
    U16x4 w; w.x = f2bf(v.x); w.y = f2bf(v.y); w.z = f2bf(v.z); w.w = f2bf(v.w);
    ((U16x4*)out)[i] = w;
  }
}

__global__ __launch_bounds__(256)
void transpose_cast_kernel(const float* __restrict__ in, u16* __restrict__ out,
                           int K, int N)   // in [K][N] fp32 -> out [N][K] bf16
{
  __shared__ u16 tile[32][33];
  const int n0 = blockIdx.x * 32, k0 = blockIdx.y * 32;
  const int tx = threadIdx.x & 31, ty = threadIdx.x >> 5;
  #pragma unroll
  for (int i = 0; i < 32; i += 8)
    tile[ty + i][tx] = f2bf(in[(size_t)(k0 + ty + i) * N + n0 + tx]);
  __syncthreads();
  #pragma unroll
  for (int i = 0; i < 32; i += 8)
    out[(size_t)(n0 + ty + i) * K + k0 + tx] = tile[tx][ty + i];
}

__global__ __launch_bounds__(256)
void transpose_v_kernel(const u16* __restrict__ vb, u16* __restrict__ out)
{
  __shared__ u16 t2[64][65];
  const int m0 = blockIdx.x * 64, f0 = blockIdx.y * 64;
  const int tx = threadIdx.x & 63, ty = threadIdx.x >> 6;
  #pragma unroll
  for (int i = 0; i < 64; i += 4)
    t2[ty + i][tx] = vb[(size_t)(f0 + ty + i) * (2 * NFFT) + m0 + tx];
  __syncthreads();
  #pragma unroll
  for (int i = 0; i < 64; i += 4)
    out[(size_t)(m0 + ty + i) * F_DIM + f0 + tx] = t2[tx][ty + i];
}

// ===========================================================================
// MFMA GEMM (unchanged, verified)
// ===========================================================================
template<int N_DIM, int K_DIM, int WMODE>
__global__ __launch_bounds__(256)
void mfma_gemm_kernel(const u16* __restrict__ A, const u16* __restrict__ B,
                      const float* __restrict__ bias, void* __restrict__ Cv)
{
  constexpr int BK = 64;
  __shared__ u16 As[128 * BK];
  __shared__ u16 Bs[128 * BK];
  const int tid  = threadIdx.x;
  const int lane = tid & 63;
  const int wid  = tid >> 6;
  const int m0 = blockIdx.x * 128;
  const int n0 = blockIdx.y * 128;

  const u16* aPtr[4]; const u16* bPtr[4];
  #pragma unroll
  for (int i = 0; i < 4; ++i) {
    const int g = tid + (i << 8);
    aPtr[i] = A + (size_t)(m0 + (g >> 3)) * K_DIM + ((g & 7) << 3);
    bPtr[i] = B + (size_t)(n0 + (g >> 3)) * K_DIM + ((g & 7) << 3);
  }

  const int wm = (wid & 1) << 6;
  const int wn = (wid >> 1) << 6;
  int aoff[4], boff[4];
  #pragma unroll
  for (int f = 0; f < 4; ++f) {
    aoff[f] = (wm + f * 16 + (lane & 15)) * BK + ((lane >> 4) << 3);
    boff[f] = (wn + f * 16 + (lane & 15)) * BK + ((lane >> 4) << 3);
  }

  f32x4 acc[4][4];
  #pragma unroll
  for (int i = 0; i < 4; ++i)
    #pragma unroll
    for (int j = 0; j < 4; ++j)
      acc[i][j] = (f32x4){0.f, 0.f, 0.f, 0.f};

  for (int k0 = 0; k0 < K_DIM; k0 += BK) {
    #pragma unroll
    for (int i = 0; i < 4; ++i) {
      __builtin_amdgcn_global_load_lds(
          (const __attribute__((address_space(1))) void*)aPtr[i],
          (__attribute__((address_space(3))) void*)&As[(((wid << 6) + (i << 8)) << 3)],
          16, 0, 0);
      aPtr[i] += BK;
    }
    #pragma unroll
    for (int i = 0; i < 4; ++i) {
      __builtin_amdgcn_global_load_lds(
          (const __attribute__((address_space(1))) void*)bPtr[i],
          (__attribute__((address_space(3))) void*)&Bs[(((wid << 6) + (i << 8)) << 3)],
          16, 0, 0);
      bPtr[i] += BK;
    }
    __syncthreads();
    #pragma unroll
    for (int kk = 0; kk < 2; ++kk) {
      bf16x8 af[4], bg[4];
      #pragma unroll
      for (int f = 0; f < 4; ++f) af[f] = *(const bf16x8*)&As[aoff[f] + kk * 32];
      #pragma unroll
      for (int f = 0; f < 4; ++f) bg[f] = *(const bf16x8*)&Bs[boff[f] + kk * 32];
      #pragma unroll
      for (int fm = 0; fm < 4; ++fm)
        #pragma unroll
        for (int fn = 0; fn < 4; ++fn)
          acc[fm][fn] = __builtin_amdgcn_mfma_f32_16x16x32_bf16(
              af[fm], bg[fn], acc[fm][fn], 0, 0, 0);
    }
    __syncthreads();
  }

  if (WMODE == 0) {
    u16* C = (u16*)Cv;
    const int b = m0 >> 13;
    const int tbase = (m0 & (L_SEQ - 1)) + wm + ((lane >> 4) << 2);
    #pragma unroll
    for (int fn = 0; fn < 4; ++fn) {
      const int n = n0 + wn + fn * 16 + (lane & 15);
      const float bv = bias[n];
      u16* row = C + ((size_t)b * N_DIM + n) * L_SEQ;
      #pragma unroll
      for (int fm = 0; fm < 4; ++fm) {
        f32x4 v = acc[fm][fn];
        U16x4 w;
        w.x = f2bf(v[0] + bv); w.y = f2bf(v[1] + bv);
        w.z = f2bf(v[2] + bv); w.w = f2bf(v[3] + bv);
        *(U16x4*)&row[tbase + fm * 16] = w;
      }
    }
  } else {
    float* C = (float*)Cv;
    #pragma unroll
    for (int fn = 0; fn < 4; ++fn) {
      const int n = n0 + wn + fn * 16 + (lane & 15);
      const float bv = bias[n];
      #pragma unroll
      for (int fm = 0; fm < 4; ++fm) {
        const int mb = m0 + wm + fm * 16 + ((lane >> 4) << 2);
        f32x4 v = acc[fm][fn];
        #pragma unroll
        for (int r = 0; r < 4; ++r)
          C[(size_t)(mb + r) * N_DIM + n] = v[r] + bv;
      }
    }
  }
}

// ===========================================================================
// Kernel A: filter MLP (unchanged, verified)
// ===========================================================================
__global__ __launch_bounds__(256)
void filter_gen_kernel(const float* __restrict__ w1, const float* __restrict__ b1,
                       const float* __restrict__ w2, const float* __restrict__ b2,
                       const float* __restrict__ decay, float* __restrict__ h_t)
{
  __shared__ float hid[64][65];
  const int tid  = threadIdx.x;
  const int tau0 = blockIdx.x * 64;
  const int c0   = blockIdx.y * 256;
  {
    const int r = tid & 63;
    const int tb = tid >> 6;
    const float w1v0 = w1[r];
    const float b1v = b1[r];
    float w1c[4], w1s[4];
    #pragma unroll
    for (int p = 0; p < 4; ++p) { w1c[p] = w1[(1 + p) * 64 + r]; w1s[p] = w1[(5 + p) * 64 + r]; }
    #pragma unroll
    for (int i = 0; i < 16; ++i) {
      const int tl = tb + i * 4;
      const int tau = tau0 + tl;
      const float off = (tau < L_SEQ) ? (float)tau : (float)(tau - NFFT);
      float acc = b1v + off * (1.0f / 8192.0f) * w1v0;
      #pragma unroll
      for (int p = 0; p < 4; ++p) {
        const double period = 4.0 + (8188.0 * p) / 3.0;
        const float freq = (float)(6.283185307179586476925287 / period);
        float sp, cp;
        sincosf(off * freq, &sp, &cp);
        acc += cp * w1c[p] + sp * w1s[p];
      }
      hid[r][tl] = sinf(acc);
    }
  }
  __syncthreads();

  const int tx = tid & 63;
  const int ty = tid >> 6;
  const int taug = tau0 + tx;
  const float mt = (taug < L_SEQ) ? (float)taug * (1.0f / 8191.0f)
                                  : (float)(NFFT - 1 - taug) * (1.0f / 8191.0f);
  const int cbase = c0 + ty * 64;
  for (int cb = 0; cb < 8; ++cb) {
    const int c8 = cbase + cb * 8;
    float acc[8];
    #pragma unroll
    for (int jj = 0; jj < 8; ++jj) acc[jj] = b2[c8 + jj];
    for (int rr = 0; rr < 64; ++rr) {
      const float hv = hid[rr][tx];
      const float4 wa = *(const float4*)&w2[rr * 1536 + c8];
      const float4 wb = *(const float4*)&w2[rr * 1536 + c8 + 4];
      acc[0] += hv * wa.x; acc[1] += hv * wa.y; acc[2] += hv * wa.z; acc[3] += hv * wa.w;
      acc[4] += hv * wb.x; acc[5] += hv * wb.y; acc[6] += hv * wb.z; acc[7] += hv * wb.w;
    }
    #pragma unroll
    for (int jj = 0; jj < 8; ++jj) {
      const int c = c8 + jj;
      const float dec = __expf(-mt * fabsf(decay[c]));
      h_t[(size_t)c * NFFT + taug] = acc[jj] * dec;
    }
  }
}

// ===========================================================================
// Kernel B: filter spectra IN PLACE (fp32 row -> bf16x2 spectrum; bias folded)
// stage 1 from global real input; final quad fused with bf16x2 16B store
// (LDS reads scalar b32; global store 16B aligned).
// ===========================================================================
__global__ __launch_bounds__(NT)
void filter_fft_kernel(float* __restrict__ hH, const float* __restrict__ bias)
{
  __shared__ float zr[NPAD];
  __shared__ float zi[NPAD];
  const int row = blockIdx.x;
  const int tid = threadIdx.x;
  float* h = hH + (size_t)row * NFFT;

  const float stw1 = -TWO_PI / 16384.0f;
  for (int g = tid; g < 1024; g += NT) {
    float x[4][4];
    #pragma unroll
    for (int k = 0; k < 4; ++k)
      #pragma unroll
      for (int m = 0; m < 4; ++m)
        x[k][m] = h[g + (m << 10) + (k << 12)];
    float yr[4][4], yi4[4][4];
    #pragma unroll
    for (int m = 0; m < 4; ++m) {
      const float t0 = x[0][m] + x[2][m];
      const float t1 = x[0][m] - x[2][m];
      const float t2 = x[1][m] + x[3][m];
      const float t3 = x[1][m] - x[3][m];
      float c1, s1, c2, s2, c3, s3;
      rot3(stw1 * (float)(g + (m << 10)), c1, s1, c2, s2, c3, s3);
      yr[0][m] = t0 + t2;           yi4[0][m] = 0.0f;
      yr[1][m] = t1*c1 + t3*s1;     yi4[1][m] = t1*s1 - t3*c1;   // y1=(t1,-t3)
      yr[2][m] = (t0 - t2)*c2;      yi4[2][m] = (t0 - t2)*s2;
      yr[3][m] = t1*c3 - t3*s3;     yi4[3][m] = t1*s3 + t3*c3;   // y3=(t1, t3)
    }
    s1_l2_store(zr, zi, g, yr, yi4);
  }
  __syncthreads();
  fwd_mid_pairs(zr, zi, tid);

  const float bo = bias[row];
  const float s = 1.0f / (float)NFFT;
  __hip_bfloat162* out2 = (__hip_bfloat162*)h;
  for (int b = tid; b < NFFT / 4; b += NT) {
    const int i0 = b << 2;
    const int p  = PAD(i0);
    const float a0r = zr[p],     a0i = zi[p];
    const float a1r = zr[p + 1], a1i = zi[p + 1];
    const float a2r = zr[p + 2], a2i = zi[p + 2];
    const float a3r = zr[p + 3], a3i = zi[p + 3];
    const float t0r = a0r + a2r, t0i = a0i + a2i;
    const float t1r = a0r - a2r, t1i = a0i - a2i;
    const float t2r = a1r + a3r, t2i = a1i + a3i;
    const float t3r = a1r - a3r, t3i = a1i - a3i;
    union { float4 f4; __hip_bfloat162 hh[4]; } o;
    o.hh[0].x = __float2bfloat16((t0r + t2r + bo) * s);
    o.hh[0].y = __float2bfloat16((t0i + t2i) * s);
    o.hh[1].x = __float2bfloat16((t1r + t3i + bo) * s);
    o.hh[1].y = __float2bfloat16((t1i - t3r) * s);
    o.hh[2].x = __float2bfloat16((t0r - t2r + bo) * s);
    o.hh[2].y = __float2bfloat16((t0i - t2i) * s);
    o.hh[3].x = __float2bfloat16((t1r - t3i + bo) * s);
    o.hh[3].y = __float2bfloat16((t1i + t3r) * s);
    *(float4*)&out2[i0] = o.f4;
  }
}

// ===========================================================================
// Kernel C: fused shortconv + 2x (FFT conv + gate); bf16 in, bf16 v rows out.
// Planar b32 LDS (round-0 layout), fused stage1 / final+spec+head /
// last-inv-pair gating (writes only t<8192).
// ===========================================================================
__global__ __launch_bounds__(NT)
void fftconv_kernel(const u16* __restrict__ up, float* __restrict__ hH,
                    const float* __restrict__ sw, const float* __restrict__ sb)
{
  __shared__ float zr[NPAD];
  __shared__ float zi[NPAD];
  const int f = blockIdx.x;
  const int tid = threadIdx.x;
  float* rowf = hH + (size_t)f * NFFT;            // o=0 spectra; later v01 out
  float* row1 = hH + (size_t)(F_DIM + f) * NFFT;  // o=1 spectra

  const u16* u0 = up + (size_t)(0 * C_IN + f) * L_SEQ;
  const u16* u1 = up + (size_t)(1 * C_IN + f) * L_SEQ;
  const float vw0 = sw[f], vw1 = sw[C_IN + f], vw2 = sw[2 * C_IN + f];
  const float vb = sb[f];

  // ===== o = 0 =====
  for (int g = tid; g < 1024; g += NT) {
    float xr[2][4], xi[2][4];
    #pragma unroll
    for (int k = 0; k < 2; ++k)
      #pragma unroll
      for (int m = 0; m < 4; ++m) {
        const int t = g + (m << 10) + (k << 12);
        xr[k][m] = conv3b(u0, t, vw0, vw1, vw2, vb);
        xi[k][m] = conv3b(u1, t, vw0, vw1, vw2, vb);
      }
    s1_zero_hi(zr, zi, g, xr, xi);
  }
  __syncthreads();
  fwd_mid_pairs(zr, zi, tid);
  fused_final_spec_head(zr, zi, (const __hip_bfloat162*)rowf, tid);
  inv_mid_pairs(zr, zi, tid);

  const int c0g = F_DIM + f;
  inv_last_gate<false>(zr, zi,
      up + (size_t)(0 * C_IN + c0g) * L_SEQ,
      up + (size_t)(1 * C_IN + c0g) * L_SEQ,
      sw[c0g], sw[C_IN + c0g], sw[2 * C_IN + c0g], sb[c0g], nullptr, tid);

  // ===== o = 1 ===== (input = gated o=0 result, t<8192 in LDS)
  for (int g = tid; g < 1024; g += NT) {
    float xr[2][4], xi[2][4];
    #pragma unroll
    for (int k = 0; k < 2; ++k)
      #pragma unroll
      for (int m = 0; m < 4; ++m) {
        const int idx = PAD(g + (m << 10) + (k << 12));
        xr[k][m] = zr[idx]; xi[k][m] = zi[idx];
      }
    s1_zero_hi(zr, zi, g, xr, xi);
  }
  __syncthreads();
  fwd_mid_pairs(zr, zi, tid);
  fused_final_spec_head(zr, zi, (const __hip_bfloat162*)row1, tid);
  inv_mid_pairs(zr, zi, tid);

  const int c1g = 2 * F_DIM + f;
  inv_last_gate<true>(zr, zi,
      up + (size_t)(0 * C_IN + c1g) * L_SEQ,
      up + (size_t)(1 * C_IN + c1g) * L_SEQ,
      sw[c1g], sw[C_IN + c1g], sw[2 * C_IN + c1g], sb[c1g], (u16*)rowf, tid);
}

// ===========================================================================
extern "C" void kernel_launch(void* const* d_in, const int* in_sizes, int n_in,
                              void* d_out, int out_size, void* d_ws, size_t ws_size,
                              hipStream_t stream)
{
  (void)in_sizes; (void)n_in; (void)out_size; (void)ws_size;
  const float* u     = (const float*)d_in[0];
  const float* fw1   = (const float*)d_in[1];
  const float* fb1   = (const float*)d_in[2];
  const float* fw2   = (const float*)d_in[3];
  const float* fb2   = (const float*)d_in[4];
  const float* decay = (const float*)d_in[5];
  const float* bias  = (const float*)d_in[6];
  const float* ipw   = (const float*)d_in[7];
  const float* ipb   = (const float*)d_in[8];
  const float* sw    = (const float*)d_in[9];
  const float* sb    = (const float*)d_in[10];
  const float* ow    = (const float*)d_in[11];
  const float* ob    = (const float*)d_in[12];
  float* out = (float*)d_out;

  char* ws = (char*)d_ws;
  u16*   up_t  = (u16*)(ws);                                // 75,497,472 B
  float* hH    = (float*)(ws + 75497472);                   // 100,663,296 B
  u16*   u_bf  = (u16*)(ws + 176160768);                    // 25,165,824 B
  u16*   ipw_t = (u16*)(ws + 201326592);                    // 3,538,944 B
  u16*   ow_t  = (u16*)(ws + 204865536);                    // 1,179,648 B
  u16*   vt_t  = (u16*)(ws + 206045184);                    // 25,165,824 B

  cast_bf16_kernel<<<dim3(12288), 256, 0, stream>>>(u, u_bf, (2 * L_SEQ * D_DIM) / 4);
  transpose_cast_kernel<<<dim3(C_IN / 32, D_DIM / 32), 256, 0, stream>>>(ipw, ipw_t, D_DIM, C_IN);
  transpose_cast_kernel<<<dim3(D_DIM / 32, F_DIM / 32), 256, 0, stream>>>(ow, ow_t, F_DIM, D_DIM);

  filter_gen_kernel<<<dim3(NFFT / 64, 1536 / 256), 256, 0, stream>>>(fw1, fb1, fw2, fb2, decay, hH);
  filter_fft_kernel<<<dim3(NORD * F_DIM), NT, 0, stream>>>(hH, bias);

  mfma_gemm_kernel<C_IN, D_DIM, 0><<<dim3(128, C_IN / 128), 256, 0, stream>>>(u_bf, ipw_t, ipb, up_t);
  fftconv_kernel<<<dim3(F_DIM), NT, 0, stream>>>(up_t, hH, sw, sb);
  transpose_v_kernel<<<dim3(NFFT / 64, F_DIM / 64), 256, 0, stream>>>((const u16*)hH, vt_t);
  mfma_gemm_kernel<D_DIM, F_DIM, 1><<<dim3(128, D_DIM / 128), 256, 0, stream>>>(vt_t, ow_t, ob, out);
}

// Round 8
// 508.053 us; speedup vs baseline: 2.0948x; 1.3524x over previous
//
#include <hip/hip_runtime.h>
#include <hip/hip_bf16.h>
#include <math.h>

#define L_SEQ 8192
#define NFFT  16384
#define NPAD  16896   // NFFT + NFFT/32 padding (floats per array)
#define F_DIM 768
#define D_DIM 768
#define C_IN  2304    // INNER = F*(ORDER+1)
#define NORD  2
#define NT    512
#define TWO_PI 6.2831853071795864769f

typedef unsigned short u16;
typedef __attribute__((ext_vector_type(8))) short bf16x8;
typedef __attribute__((ext_vector_type(4))) float f32x4;
struct __align__(8) U16x4 { u16 x, y, z, w; };

__device__ __forceinline__ float bf2f(u16 v) {
  unsigned u = ((unsigned)v) << 16; float f; __builtin_memcpy(&f, &u, 4); return f;
}
__device__ __forceinline__ u16 f2bf(float f) {
  __hip_bfloat16 h = __float2bfloat16(f); u16 r; __builtin_memcpy(&r, &h, 2); return r;
}

// LDS pad: bank(i) shifts by 1 every 32 floats -> all FFT strides <=2-way (free).
// NOTE: pad stride 1 breaks 8/16B alignment classes -> LDS access must stay b32.
__device__ __forceinline__ int PAD(int i) { return i + (i >> 5); }

__device__ __forceinline__ void rot3(float ang, float& c1, float& s1,
                                     float& c2, float& s2, float& c3, float& s3)
{
  __sincosf(ang, &s1, &c1);
  c2 = c1 * c1 - s1 * s1; s2 = 2.0f * c1 * s1;
  c3 = c1 * c2 - s1 * s2; s3 = c1 * s2 + s1 * c2;
}

// depthwise conv3 on a bf16 row, SAME padding (XLA cross-correlation)
__device__ __forceinline__ float conv3b(const u16* __restrict__ row, int t,
                                        float w0, float w1, float w2, float sb)
{
  float l = (t > 0)         ? bf2f(row[t - 1]) : 0.0f;
  float c = bf2f(row[t]);
  float r = (t < L_SEQ - 1) ? bf2f(row[t + 1]) : 0.0f;
  return w0 * l + w1 * c + w2 * r + sb;
}

// ===========================================================================
// Radix-4 FFT, N = 16384 = 4^7, PLANAR zr/zi in LDS (b32, 2-way-free PAD).
// Stage algebra verbatim from the verified round-0/round-7 kernels.
// ===========================================================================

// layer-2 (stage 10) + planar stores of the first fwd pair. g in [0,1024).
__device__ __forceinline__ void s1_l2_store(float* zr, float* zi, int g,
    const float yr[4][4], const float yi4[4][4])
{
  const float stw2 = -TWO_PI / 4096.0f;
  float c1, s1, c2, s2, c3, s3;
  rot3(stw2 * (float)g, c1, s1, c2, s2, c3, s3);
  #pragma unroll
  for (int k = 0; k < 4; ++k) {
    float t0r = yr[k][0] + yr[k][2], t0i = yi4[k][0] + yi4[k][2];
    float t1r = yr[k][0] - yr[k][2], t1i = yi4[k][0] - yi4[k][2];
    float t2r = yr[k][1] + yr[k][3], t2i = yi4[k][1] + yi4[k][3];
    float t3r = yr[k][1] - yr[k][3], t3i = yi4[k][1] - yi4[k][3];
    float o0r = t0r + t2r, o0i = t0i + t2i;
    float o1r = t1r + t3i, o1i = t1i - t3r;
    float o2r = t0r - t2r, o2i = t0i - t2i;
    float o3r = t1r - t3i, o3i = t1i + t3r;
    const int i0 = g + (k << 12);
    zr[PAD(i0       )] = o0r;               zi[PAD(i0       )] = o0i;
    zr[PAD(i0 + 1024)] = o1r*c1 - o1i*s1;   zi[PAD(i0 + 1024)] = o1r*s1 + o1i*c1;
    zr[PAD(i0 + 2048)] = o2r*c2 - o2i*s2;   zi[PAD(i0 + 2048)] = o2r*s2 + o2i*c2;
    zr[PAD(i0 + 3072)] = o3r*c3 - o3i*s3;   zi[PAD(i0 + 3072)] = o3r*s3 + o3i*c3;
  }
}

// stage-1 layer-1 with k=2,3 inputs == 0 (zero-padded upper half).
__device__ __forceinline__ void s1_zero_hi(float* zr, float* zi, int g,
    const float xr[2][4], const float xi[2][4])
{
  const float stw1 = -TWO_PI / 16384.0f;
  float yr[4][4], yi4[4][4];
  #pragma unroll
  for (int m = 0; m < 4; ++m) {
    const float x0r = xr[0][m], x0i = xi[0][m];
    const float x1r = xr[1][m], x1i = xi[1][m];
    const float y0r = x0r + x1r, y0i = x0i + x1i;
    const float y1r = x0r + x1i, y1i = x0i - x1r;
    const float y2r = x0r - x1r, y2i = x0i - x1i;
    const float y3r = x0r - x1i, y3i = x0i + x1r;
    float c1, s1, c2, s2, c3, s3;
    rot3(stw1 * (float)(g + (m << 10)), c1, s1, c2, s2, c3, s3);
    yr[0][m] = y0r;               yi4[0][m] = y0i;
    yr[1][m] = y1r*c1 - y1i*s1;   yi4[1][m] = y1r*s1 + y1i*c1;
    yr[2][m] = y2r*c2 - y2i*s2;   yi4[2][m] = y2r*s2 + y2i*c2;
    yr[3][m] = y3r*c3 - y3i*s3;   yi4[3][m] = y3r*s3 + y3i*c3;
  }
  s1_l2_store(zr, zi, g, yr, yi4);
}

// fwd middle pairs (8,6)(4,2) — planar body verbatim from round 0
__device__ __forceinline__ void fwd_mid_pairs(float* zr, float* zi, int tid)
{
  #pragma unroll
  for (int lq = 8; lq >= 4; lq -= 4) {
    const int q  = 1 << lq;
    const int q4 = q >> 2;
    const float stw1 = -TWO_PI / (float)(q << 2);
    const float stw2 = -TWO_PI / (float)q;
    for (int g = tid; g < NFFT / 16; g += NT) {
      const int j    = g & (q4 - 1);
      const int base = ((g >> (lq - 2)) << (lq + 2)) + j;
      float xr[4][4], xi4[4][4];
      #pragma unroll
      for (int k = 0; k < 4; ++k)
        #pragma unroll
        for (int m = 0; m < 4; ++m) {
          const int idx = PAD(base + m * q4 + k * q);
          xr[k][m] = zr[idx]; xi4[k][m] = zi[idx];
        }
      #pragma unroll
      for (int m = 0; m < 4; ++m) {
        float t0r = xr[0][m] + xr[2][m], t0i = xi4[0][m] + xi4[2][m];
        float t1r = xr[0][m] - xr[2][m], t1i = xi4[0][m] - xi4[2][m];
        float t2r = xr[1][m] + xr[3][m], t2i = xi4[1][m] + xi4[3][m];
        float t3r = xr[1][m] - xr[3][m], t3i = xi4[1][m] - xi4[3][m];
        float y0r = t0r + t2r, y0i = t0i + t2i;
        float y1r = t1r + t3i, y1i = t1i - t3r;
        float y2r = t0r - t2r, y2i = t0i - t2i;
        float y3r = t1r - t3i, y3i = t1i + t3r;
        float c1, s1, c2, s2, c3, s3;
        rot3(stw1 * (float)(j + m * q4), c1, s1, c2, s2, c3, s3);
        xr[0][m] = y0r;                xi4[0][m] = y0i;
        xr[1][m] = y1r * c1 - y1i * s1; xi4[1][m] = y1r * s1 + y1i * c1;
        xr[2][m] = y2r * c2 - y2i * s2; xi4[2][m] = y2r * s2 + y2i * c2;
        xr[3][m] = y3r * c3 - y3i * s3; xi4[3][m] = y3r * s3 + y3i * c3;
      }
      float c1, s1, c2, s2, c3, s3;
      rot3(stw2 * (float)j, c1, s1, c2, s2, c3, s3);
      #pragma unroll
      for (int k = 0; k < 4; ++k) {
        float t0r = xr[k][0] + xr[k][2], t0i = xi4[k][0] + xi4[k][2];
        float t1r = xr[k][0] - xr[k][2], t1i = xi4[k][0] - xi4[k][2];
        float t2r = xr[k][1] + xr[k][3], t2i = xi4[k][1] + xi4[k][3];
        float t3r = xr[k][1] - xr[k][3], t3i = xi4[k][1] - xi4[k][3];
        float y0r = t0r + t2r, y0i = t0i + t2i;
        float y1r = t1r + t3i, y1i = t1i - t3r;
        float y2r = t0r - t2r, y2i = t0i - t2i;
        float y3r = t1r - t3i, y3i = t1i + t3r;
        const int i0 = base + k * q;
        zr[PAD(i0         )] = y0r;            zi[PAD(i0         )] = y0i;
        zr[PAD(i0 +     q4)] = y1r*c1 - y1i*s1; zi[PAD(i0 +     q4)] = y1r*s1 + y1i*c1;
        zr[PAD(i0 + 2 * q4)] = y2r*c2 - y2i*s2; zi[PAD(i0 + 2 * q4)] = y2r*s2 + y2i*c2;
        zr[PAD(i0 + 3 * q4)] = y3r*c3 - y3i*s3; zi[PAD(i0 + 3 * q4)] = y3r*s3 + y3i*c3;
      }
    }
    __syncthreads();
  }
}

// fwd final radix-4 + spectrum multiply + inv head fused in registers (b32 LDS).
__device__ __forceinline__ void fused_final_spec_head(float* zr, float* zi,
    const __hip_bfloat162* __restrict__ H, int tid)
{
  for (int b = tid; b < NFFT / 4; b += NT) {
    const int i0 = b << 2;
    const int p  = PAD(i0);                  // quad never crosses pad stripe
    const float a0r = zr[p],     a0i = zi[p];
    const float a1r = zr[p + 1], a1i = zi[p + 1];
    const float a2r = zr[p + 2], a2i = zi[p + 2];
    const float a3r = zr[p + 3], a3i = zi[p + 3];
    float t0r = a0r + a2r, t0i = a0i + a2i;
    float t1r = a0r - a2r, t1i = a0i - a2i;
    float t2r = a1r + a3r, t2i = a1i + a3i;
    float t3r = a1r - a3r, t3i = a1i - a3i;
    float y0r = t0r + t2r, y0i = t0i + t2i;
    float y1r = t1r + t3i, y1i = t1i - t3r;
    float y2r = t0r - t2r, y2i = t0i - t2i;
    float y3r = t1r - t3i, y3i = t1i + t3r;
    const float4 hq = *(const float4*)&H[i0];
    __hip_bfloat162 h0, h1, h2, h3;
    __builtin_memcpy(&h0, &hq.x, 4); __builtin_memcpy(&h1, &hq.y, 4);
    __builtin_memcpy(&h2, &hq.z, 4); __builtin_memcpy(&h3, &hq.w, 4);
    float hr, hi;
    hr = __bfloat162float(h0.x); hi = __bfloat162float(h0.y);
    const float u0r = y0r*hr - y0i*hi, u0i = y0r*hi + y0i*hr;
    hr = __bfloat162float(h1.x); hi = __bfloat162float(h1.y);
    const float u1r = y1r*hr - y1i*hi, u1i = y1r*hi + y1i*hr;
    hr = __bfloat162float(h2.x); hi = __bfloat162float(h2.y);
    const float u2r = y2r*hr - y2i*hi, u2i = y2r*hi + y2i*hr;
    hr = __bfloat162float(h3.x); hi = __bfloat162float(h3.y);
    const float u3r = y3r*hr - y3i*hi, u3i = y3r*hi + y3i*hr;
    const float e0r = u0r + u2r, e0i = u0i + u2i;
    const float e1r = u0r - u2r, e1i = u0i - u2i;
    const float f0r = u1r + u3r, f0i = u1i + u3i;
    const float f1r = u1r - u3r, f1i = u1i - u3i;
    zr[p]     = e0r + f0r; zi[p]     = e0i + f0i;
    zr[p + 1] = e1r - f1i; zi[p + 1] = e1i + f1r;
    zr[p + 2] = e0r - f0r; zi[p + 2] = e0i - f0i;
    zr[p + 3] = e1r + f1i; zi[p + 3] = e1i - f1r;
  }
  __syncthreads();
}

// inv middle pairs (2,4)(6,8) — planar body verbatim from round 0
__device__ __forceinline__ void inv_mid_pairs(float* zr, float* zi, int tid)
{
  #pragma unroll
  for (int lq = 2; lq <= 6; lq += 4) {
    const int q = 1 << lq;
    const int Q = q << 2;
    const float stw1 = TWO_PI / (float)(q << 2);
    const float stw2 = TWO_PI / (float)(Q << 2);
    for (int g = tid; g < NFFT / 16; g += NT) {
      const int j    = g & (q - 1);
      const int base = ((g >> lq) << (lq + 4)) + j;
      float xr[4][4], xi4[4][4];
      #pragma unroll
      for (int k = 0; k < 4; ++k)
        #pragma unroll
        for (int m = 0; m < 4; ++m) {
          const int idx = PAD(base + m * q + k * Q);
          xr[k][m] = zr[idx]; xi4[k][m] = zi[idx];
        }
      {
        float c1, s1, c2, s2, c3, s3;
        rot3(stw1 * (float)j, c1, s1, c2, s2, c3, s3);
        #pragma unroll
        for (int k = 0; k < 4; ++k) {
          float u0r = xr[k][0], u0i = xi4[k][0];
          float u1r = xr[k][1]*c1 - xi4[k][1]*s1, u1i = xr[k][1]*s1 + xi4[k][1]*c1;
          float u2r = xr[k][2]*c2 - xi4[k][2]*s2, u2i = xr[k][2]*s2 + xi4[k][2]*c2;
          float u3r = xr[k][3]*c3 - xi4[k][3]*s3, u3i = xr[k][3]*s3 + xi4[k][3]*c3;
          float e0r = u0r + u2r, e0i = u0i + u2i;
          float e1r = u0r - u2r, e1i = u0i - u2i;
          float f0r = u1r + u3r, f0i = u1i + u3i;
          float f1r = u1r - u3r, f1i = u1i - u3i;
          xr[k][0] = e0r + f0r; xi4[k][0] = e0i + f0i;
          xr[k][1] = e1r - f1i; xi4[k][1] = e1i + f1r;
          xr[k][2] = e0r - f0r; xi4[k][2] = e0i - f0i;
          xr[k][3] = e1r + f1i; xi4[k][3] = e1i - f1r;
        }
      }
      #pragma unroll
      for (int m = 0; m < 4; ++m) {
        float c1, s1, c2, s2, c3, s3;
        rot3(stw2 * (float)(j + m * q), c1, s1, c2, s2, c3, s3);
        float u0r = xr[0][m], u0i = xi4[0][m];
        float u1r = xr[1][m]*c1 - xi4[1][m]*s1, u1i = xr[1][m]*s1 + xi4[1][m]*c1;
        float u2r = xr[2][m]*c2 - xi4[2][m]*s2, u2i = xr[2][m]*s2 + xi4[2][m]*c2;
        float u3r = xr[3][m]*c3 - xi4[3][m]*s3, u3i = xr[3][m]*s3 + xi4[3][m]*c3;
        float e0r = u0r + u2r, e0i = u0i + u2i;
        float e1r = u0r - u2r, e1i = u0i - u2i;
        float f0r = u1r + u3r, f0i = u1i + u3i;
        float f1r = u1r - u3r, f1i = u1i - u3i;
        const int i0 = base + m * q;
        zr[PAD(i0        )] = e0r + f0r; zi[PAD(i0        )] = e0i + f0i;
        zr[PAD(i0 +     Q)] = e1r - f1i; zi[PAD(i0 +     Q)] = e1i + f1r;
        zr[PAD(i0 + 2 * Q)] = e0r - f0r; zi[PAD(i0 + 2 * Q)] = e0i - f0i;
        zr[PAD(i0 + 3 * Q)] = e1r + f1i; zi[PAD(i0 + 3 * Q)] = e1i - f1r;
      }
    }
    __syncthreads();
  }
}

// inv last pair (10,12) fused with gate; outputs only t<8192 (k=0,1).
template<bool TO_GLOBAL>
__device__ __forceinline__ void inv_last_gate(float* zr, float* zi,
    const u16* __restrict__ gr0, const u16* __restrict__ gr1,
    float w0, float w1, float w2, float wb, u16* __restrict__ outv, int tid)
{
  const float stw1 = TWO_PI / 4096.0f;    // 2pi/(4q), q=1024
  const float stw2 = TWO_PI / 16384.0f;   // 2pi/(4Q), Q=4096
  for (int g = tid; g < 1024; g += NT) {
    float xr[4][4], xi4[4][4];
    #pragma unroll
    for (int k = 0; k < 4; ++k)
      #pragma unroll
      for (int m = 0; m < 4; ++m) {
        const int idx = PAD(g + (m << 10) + (k << 12));
        xr[k][m] = zr[idx]; xi4[k][m] = zi[idx];
      }
    {                                      // layer 1: stage 10, j1 = g
      float c1, s1, c2, s2, c3, s3;
      rot3(stw1 * (float)g, c1, s1, c2, s2, c3, s3);
      #pragma unroll
      for (int k = 0; k < 4; ++k) {
        float u0r = xr[k][0], u0i = xi4[k][0];
        float u1r = xr[k][1]*c1 - xi4[k][1]*s1, u1i = xr[k][1]*s1 + xi4[k][1]*c1;
        float u2r = xr[k][2]*c2 - xi4[k][2]*s2, u2i = xr[k][2]*s2 + xi4[k][2]*c2;
        float u3r = xr[k][3]*c3 - xi4[k][3]*s3, u3i = xr[k][3]*s3 + xi4[k][3]*c3;
        float e0r = u0r + u2r, e0i = u0i + u2i;
        float e1r = u0r - u2r, e1i = u0i - u2i;
        float f0r = u1r + u3r, f0i = u1i + u3i;
        float f1r = u1r - u3r, f1i = u1i - u3i;
        xr[k][0] = e0r + f0r; xi4[k][0] = e0i + f0i;
        xr[k][1] = e1r - f1i; xi4[k][1] = e1i + f1r;
        xr[k][2] = e0r - f0r; xi4[k][2] = e0i - f0i;
        xr[k][3] = e1r + f1i; xi4[k][3] = e1i - f1r;
      }
    }
    #pragma unroll
    for (int m = 0; m < 4; ++m) {          // layer 2: stage 12, j2 = g + m*1024
      float c1, s1, c2, s2, c3, s3;
      rot3(stw2 * (float)(g + (m << 10)), c1, s1, c2, s2, c3, s3);
      float u0r = xr[0][m], u0i = xi4[0][m];
      float u1r = xr[1][m]*c1 - xi4[1][m]*s1, u1i = xr[1][m]*s1 + xi4[1][m]*c1;
      float u2r = xr[2][m]*c2 - xi4[2][m]*s2, u2i = xr[2][m]*s2 + xi4[2][m]*c2;
      float u3r = xr[3][m]*c3 - xi4[3][m]*s3, u3i = xr[3][m]*s3 + xi4[3][m]*c3;
      float e0r = u0r + u2r, e0i = u0i + u2i;
      float e1r = u0r - u2r, e1i = u0i - u2i;
      float f0r = u1r + u3r, f0i = u1i + u3i;
      float f1r = u1r - u3r, f1i = u1i - u3i;
      const int t0 = g + (m << 10);        // k=0 output, t0 < 4096
      const int t1 = t0 + 4096;            // k=1 output, t1 < 8192
      const float o0r = e0r + f0r, o0i = e0i + f0i;
      const float o1r = e1r - f1i, o1i = e1i + f1r;
      const float a0 = conv3b(gr0, t0, w0, w1, w2, wb);
      const float b0 = conv3b(gr1, t0, w0, w1, w2, wb);
      const float a1 = conv3b(gr0, t1, w0, w1, w2, wb);
      const float b1 = conv3b(gr1, t1, w0, w1, w2, wb);
      if (TO_GLOBAL) {
        outv[t0]         = f2bf(o0r * a0);
        outv[L_SEQ + t0] = f2bf(o0i * b0);
        outv[t1]         = f2bf(o1r * a1);
        outv[L_SEQ + t1] = f2bf(o1i * b1);
      } else {
        zr[PAD(t0)] = o0r * a0;  zi[PAD(t0)] = o0i * b0;
        zr[PAD(t1)] = o1r * a1;  zi[PAD(t1)] = o1i * b1;
      }
      // k=2,3 outputs (t >= 8192) are never needed: not written.
    }
  }
  if (!TO_GLOBAL) __syncthreads();
}

// ===========================================================================
// Prep kernels
// ===========================================================================
__global__ __launch_bounds__(256)
void cast_bf16_kernel(const float* __restrict__ in, u16* __restrict__ out, int n4)
{
  int i = blockIdx.x * 256 + threadIdx.x;
  if (i < n4) {
    float4 v = ((const float4*)in)[i];
    U16x4 w; w.x = f2bf(v.x); w.y = f2bf(v.y); w.z = f2bf(v.z); w.w = f2bf(v.w);
    ((U16x4*)out)[i] = w;
  }
}

__global__ __launch_bounds__(256)
void transpose_cast_kernel(const float* __restrict__ in, u16* __restrict__ out,
                           int K, int N)   // in [K][N] fp32 -> out [N][K] bf16
{
  __shared__ u16 tile[32][33];
  const int n0 = blockIdx.x * 32, k0 = blockIdx.y * 32;
  const int tx = threadIdx.x & 31, ty = threadIdx.x >> 5;
  #pragma unroll
  for (int i = 0; i < 32; i += 8)
    tile[ty + i][tx] = f2bf(in[(size_t)(k0 + ty + i) * N + n0 + tx]);
  __syncthreads();
  #pragma unroll
  for (int i = 0; i < 32; i += 8)
    out[(size_t)(n0 + ty + i) * K + k0 + tx] = tile[tx][ty + i];
}

__global__ __launch_bounds__(256)
void transpose_v_kernel(const u16* __restrict__ vb, u16* __restrict__ out)
{
  __shared__ u16 t2[64][65];
  const int m0 = blockIdx.x * 64, f0 = blockIdx.y * 64;
  const int tx = threadIdx.x & 63, ty = threadIdx.x >> 6;
  #pragma unroll
  for (int i = 0; i < 64; i += 4)
    t2[ty + i][tx] = vb[(size_t)(f0 + ty + i) * (2 * NFFT) + m0 + tx];
  __syncthreads();
  #pragma unroll
  for (int i = 0; i < 64; i += 4)
    out[(size_t)(m0 + ty + i) * F_DIM + f0 + tx] = t2[tx][ty + i];
}

// hid[16384][64] bf16: first MLP layer on the sine positional embedding.
// Same math as the verified filter_gen phase 1.
__global__ __launch_bounds__(256)
void hid_gen_kernel(const float* __restrict__ w1, const float* __restrict__ b1,
                    u16* __restrict__ hidb)
{
  const int tid = threadIdx.x;
  const int r  = tid & 63;
  const int tb = tid >> 6;
  const float w1v0 = w1[r];
  const float b1v  = b1[r];
  float w1c[4], w1s[4];
  #pragma unroll
  for (int p = 0; p < 4; ++p) { w1c[p] = w1[(1 + p) * 64 + r]; w1s[p] = w1[(5 + p) * 64 + r]; }
  const int tau0 = blockIdx.x * 16;
  #pragma unroll
  for (int i = 0; i < 4; ++i) {
    const int tau = tau0 + tb + i * 4;
    const float off = (tau < L_SEQ) ? (float)tau : (float)(tau - NFFT);
    float acc = b1v + off * (1.0f / 8192.0f) * w1v0;
    #pragma unroll
    for (int p = 0; p < 4; ++p) {
      const double period = 4.0 + (8188.0 * p) / 3.0;
      const float freq = (float)(6.283185307179586476925287 / period);
      float sp, cp;
      sincosf(off * freq, &sp, &cp);
      acc += cp * w1c[p] + sp * w1s[p];
    }
    hidb[(size_t)tau * 64 + r] = f2bf(sinf(acc));
  }
}

// ===========================================================================
// MFMA GEMM.  WMODE 0: up_t bf16 batch layout.  WMODE 1: fp32 [M][N].
// WMODE 2: filter h path — C = bf16 rows [n][tau] strided 2*NFFT u16;
//          val = (acc + b2[n]) * exp(-mt(tau)*|decay[n]|).
// ===========================================================================
template<int N_DIM, int K_DIM, int WMODE>
__global__ __launch_bounds__(256)
void mfma_gemm_kernel(const u16* __restrict__ A, const u16* __restrict__ B,
                      const float* __restrict__ bias, void* __restrict__ Cv,
                      const float* __restrict__ dk)
{
  constexpr int BK = 64;
  __shared__ u16 As[128 * BK];
  __shared__ u16 Bs[128 * BK];
  const int tid  = threadIdx.x;
  const int lane = tid & 63;
  const int wid  = tid >> 6;
  const int m0 = blockIdx.x * 128;
  const int n0 = blockIdx.y * 128;

  const u16* aPtr[4]; const u16* bPtr[4];
  #pragma unroll
  for (int i = 0; i < 4; ++i) {
    const int g = tid + (i << 8);
    aPtr[i] = A + (size_t)(m0 + (g >> 3)) * K_DIM + ((g & 7) << 3);
    bPtr[i] = B + (size_t)(n0 + (g >> 3)) * K_DIM + ((g & 7) << 3);
  }

  const int wm = (wid & 1) << 6;
  const int wn = (wid >> 1) << 6;
  int aoff[4], boff[4];
  #pragma unroll
  for (int f = 0; f < 4; ++f) {
    aoff[f] = (wm + f * 16 + (lane & 15)) * BK + ((lane >> 4) << 3);
    boff[f] = (wn + f * 16 + (lane & 15)) * BK + ((lane >> 4) << 3);
  }

  f32x4 acc[4][4];
  #pragma unroll
  for (int i = 0; i < 4; ++i)
    #pragma unroll
    for (int j = 0; j < 4; ++j)
      acc[i][j] = (f32x4){0.f, 0.f, 0.f, 0.f};

  for (int k0 = 0; k0 < K_DIM; k0 += BK) {
    #pragma unroll
    for (int i = 0; i < 4; ++i) {
      __builtin_amdgcn_global_load_lds(
          (const __attribute__((address_space(1))) void*)aPtr[i],
          (__attribute__((address_space(3))) void*)&As[(((wid << 6) + (i << 8)) << 3)],
          16, 0, 0);
      aPtr[i] += BK;
    }
    #pragma unroll
    for (int i = 0; i < 4; ++i) {
      __builtin_amdgcn_global_load_lds(
          (const __attribute__((address_space(1))) void*)bPtr[i],
          (__attribute__((address_space(3))) void*)&Bs[(((wid << 6) + (i << 8)) << 3)],
          16, 0, 0);
      bPtr[i] += BK;
    }
    __syncthreads();
    #pragma unroll
    for (int kk = 0; kk < 2; ++kk) {
      bf16x8 af[4], bg[4];
      #pragma unroll
      for (int f = 0; f < 4; ++f) af[f] = *(const bf16x8*)&As[aoff[f] + kk * 32];
      #pragma unroll
      for (int f = 0; f < 4; ++f) bg[f] = *(const bf16x8*)&Bs[boff[f] + kk * 32];
      #pragma unroll
      for (int fm = 0; fm < 4; ++fm)
        #pragma unroll
        for (int fn = 0; fn < 4; ++fn)
          acc[fm][fn] = __builtin_amdgcn_mfma_f32_16x16x32_bf16(
              af[fm], bg[fn], acc[fm][fn], 0, 0, 0);
    }
    __syncthreads();
  }

  if (WMODE == 0) {
    u16* C = (u16*)Cv;
    const int b = m0 >> 13;
    const int tbase = (m0 & (L_SEQ - 1)) + wm + ((lane >> 4) << 2);
    #pragma unroll
    for (int fn = 0; fn < 4; ++fn) {
      const int n = n0 + wn + fn * 16 + (lane & 15);
      const float bv = bias[n];
      u16* row = C + ((size_t)b * N_DIM + n) * L_SEQ;
      #pragma unroll
      for (int fm = 0; fm < 4; ++fm) {
        f32x4 v = acc[fm][fn];
        U16x4 w;
        w.x = f2bf(v[0] + bv); w.y = f2bf(v[1] + bv);
        w.z = f2bf(v[2] + bv); w.w = f2bf(v[3] + bv);
        *(U16x4*)&row[tbase + fm * 16] = w;
      }
    }
  } else if (WMODE == 1) {
    float* C = (float*)Cv;
    #pragma unroll
    for (int fn = 0; fn < 4; ++fn) {
      const int n = n0 + wn + fn * 16 + (lane & 15);
      const float bv = bias[n];
      #pragma unroll
      for (int fm = 0; fm < 4; ++fm) {
        const int mb = m0 + wm + fm * 16 + ((lane >> 4) << 2);
        f32x4 v = acc[fm][fn];
        #pragma unroll
        for (int r = 0; r < 4; ++r)
          C[(size_t)(mb + r) * N_DIM + n] = v[r] + bv;
      }
    }
  } else {  // WMODE == 2: h rows bf16 at [n][tau], stride 2*NFFT u16
    u16* C = (u16*)Cv;
    #pragma unroll
    for (int fn = 0; fn < 4; ++fn) {
      const int n = n0 + wn + fn * 16 + (lane & 15);
      const float bv = bias[n];
      const float ad = fabsf(dk[n]);
      u16* row = C + (size_t)n * (2 * NFFT);
      #pragma unroll
      for (int fm = 0; fm < 4; ++fm) {
        const int mq = m0 + wm + fm * 16 + ((lane >> 4) << 2);
        f32x4 v = acc[fm][fn];
        U16x4 w;
        #pragma unroll
        for (int r = 0; r < 4; ++r) {
          const int t = mq + r;
          const float mt = (t < L_SEQ) ? (float)t * (1.0f / 8191.0f)
                                       : (float)(NFFT - 1 - t) * (1.0f / 8191.0f);
          const float dec = __expf(-mt * ad);
          ((u16*)&w)[r] = f2bf((v[r] + bv) * dec);
        }
        *(U16x4*)&row[mq] = w;
      }
    }
  }
}

// ===========================================================================
// Kernel B: filter spectra — reads bf16 h row (first 32KB of the 64KB hH row),
// writes bf16x2 spectrum over the full row. All input reads complete before
// the first barrier; spectrum writes happen only in the epilogue -> safe.
// ===========================================================================
__global__ __launch_bounds__(NT)
void filter_fft_kernel(float* __restrict__ hH, const float* __restrict__ bias)
{
  __shared__ float zr[NPAD];
  __shared__ float zi[NPAD];
  const int row = blockIdx.x;
  const int tid = threadIdx.x;
  float* h = hH + (size_t)row * NFFT;
  const u16* hb = (const u16*)h;

  const float stw1 = -TWO_PI / 16384.0f;
  for (int g = tid; g < 1024; g += NT) {
    float x[4][4];
    #pragma unroll
    for (int k = 0; k < 4; ++k)
      #pragma unroll
      for (int m = 0; m < 4; ++m)
        x[k][m] = bf2f(hb[g + (m << 10) + (k << 12)]);
    float yr[4][4], yi4[4][4];
    #pragma unroll
    for (int m = 0; m < 4; ++m) {
      const float t0 = x[0][m] + x[2][m];
      const float t1 = x[0][m] - x[2][m];
      const float t2 = x[1][m] + x[3][m];
      const float t3 = x[1][m] - x[3][m];
      float c1, s1, c2, s2, c3, s3;
      rot3(stw1 * (float)(g + (m << 10)), c1, s1, c2, s2, c3, s3);
      yr[0][m] = t0 + t2;           yi4[0][m] = 0.0f;
      yr[1][m] = t1*c1 + t3*s1;     yi4[1][m] = t1*s1 - t3*c1;   // y1=(t1,-t3)
      yr[2][m] = (t0 - t2)*c2;      yi4[2][m] = (t0 - t2)*s2;
      yr[3][m] = t1*c3 - t3*s3;     yi4[3][m] = t1*s3 + t3*c3;   // y3=(t1, t3)
    }
    s1_l2_store(zr, zi, g, yr, yi4);
  }
  __syncthreads();
  fwd_mid_pairs(zr, zi, tid);

  const float bo = bias[row];
  const float s = 1.0f / (float)NFFT;
  __hip_bfloat162* out2 = (__hip_bfloat162*)h;
  for (int b = tid; b < NFFT / 4; b += NT) {
    const int i0 = b << 2;
    const int p  = PAD(i0);
    const float a0r = zr[p],     a0i = zi[p];
    const float a1r = zr[p + 1], a1i = zi[p + 1];
    const float a2r = zr[p + 2], a2i = zi[p + 2];
    const float a3r = zr[p + 3], a3i = zi[p + 3];
    const float t0r = a0r + a2r, t0i = a0i + a2i;
    const float t1r = a0r - a2r, t1i = a0i - a2i;
    const float t2r = a1r + a3r, t2i = a1i + a3i;
    const float t3r = a1r - a3r, t3i = a1i - a3i;
    union { float4 f4; __hip_bfloat162 hh[4]; } o;
    o.hh[0].x = __float2bfloat16((t0r + t2r + bo) * s);
    o.hh[0].y = __float2bfloat16((t0i + t2i) * s);
    o.hh[1].x = __float2bfloat16((t1r + t3i + bo) * s);
    o.hh[1].y = __float2bfloat16((t1i - t3r) * s);
    o.hh[2].x = __float2bfloat16((t0r - t2r + bo) * s);
    o.hh[2].y = __float2bfloat16((t0i - t2i) * s);
    o.hh[3].x = __float2bfloat16((t1r - t3i + bo) * s);
    o.hh[3].y = __float2bfloat16((t1i + t3r) * s);
    *(float4*)&out2[i0] = o.f4;
  }
}

// ===========================================================================
// Kernel C: fused shortconv + 2x (FFT conv + gate) — unchanged from round 7.
// ===========================================================================
__global__ __launch_bounds__(NT)
void fftconv_kernel(const u16* __restrict__ up, float* __restrict__ hH,
                    const float* __restrict__ sw, const float* __restrict__ sb)
{
  __shared__ float zr[NPAD];
  __shared__ float zi[NPAD];
  const int f = blockIdx.x;
  const int tid = threadIdx.x;
  float* rowf = hH + (size_t)f * NFFT;            // o=0 spectra; later v01 out
  float* row1 = hH + (size_t)(F_DIM + f) * NFFT;  // o=1 spectra

  const u16* u0 = up + (size_t)(0 * C_IN + f) * L_SEQ;
  const u16* u1 = up + (size_t)(1 * C_IN + f) * L_SEQ;
  const float vw0 = sw[f], vw1 = sw[C_IN + f], vw2 = sw[2 * C_IN + f];
  const float vb = sb[f];

  // ===== o = 0 =====
  for (int g = tid; g < 1024; g += NT) {
    float xr[2][4], xi[2][4];
    #pragma unroll
    for (int k = 0; k < 2; ++k)
      #pragma unroll
      for (int m = 0; m < 4; ++m) {
        const int t = g + (m << 10) + (k << 12);
        xr[k][m] = conv3b(u0, t, vw0, vw1, vw2, vb);
        xi[k][m] = conv3b(u1, t, vw0, vw1, vw2, vb);
      }
    s1_zero_hi(zr, zi, g, xr, xi);
  }
  __syncthreads();
  fwd_mid_pairs(zr, zi, tid);
  fused_final_spec_head(zr, zi, (const __hip_bfloat162*)rowf, tid);
  inv_mid_pairs(zr, zi, tid);

  const int c0g = F_DIM + f;
  inv_last_gate<false>(zr, zi,
      up + (size_t)(0 * C_IN + c0g) * L_SEQ,
      up + (size_t)(1 * C_IN + c0g) * L_SEQ,
      sw[c0g], sw[C_IN + c0g], sw[2 * C_IN + c0g], sb[c0g], nullptr, tid);

  // ===== o = 1 ===== (input = gated o=0 result, t<8192 in LDS)
  for (int g = tid; g < 1024; g += NT) {
    float xr[2][4], xi[2][4];
    #pragma unroll
    for (int k = 0; k < 2; ++k)
      #pragma unroll
      for (int m = 0; m < 4; ++m) {
        const int idx = PAD(g + (m << 10) + (k << 12));
        xr[k][m] = zr[idx]; xi[k][m] = zi[idx];
      }
    s1_zero_hi(zr, zi, g, xr, xi);
  }
  __syncthreads();
  fwd_mid_pairs(zr, zi, tid);
  fused_final_spec_head(zr, zi, (const __hip_bfloat162*)row1, tid);
  inv_mid_pairs(zr, zi, tid);

  const int c1g = 2 * F_DIM + f;
  inv_last_gate<true>(zr, zi,
      up + (size_t)(0 * C_IN + c1g) * L_SEQ,
      up + (size_t)(1 * C_IN + c1g) * L_SEQ,
      sw[c1g], sw[C_IN + c1g], sw[2 * C_IN + c1g], sb[c1g], (u16*)rowf, tid);
}

// ===========================================================================
extern "C" void kernel_launch(void* const* d_in, const int* in_sizes, int n_in,
                              void* d_out, int out_size, void* d_ws, size_t ws_size,
                              hipStream_t stream)
{
  (void)in_sizes; (void)n_in; (void)out_size; (void)ws_size;
  const float* u     = (const float*)d_in[0];
  const float* fw1   = (const float*)d_in[1];
  const float* fb1   = (const float*)d_in[2];
  const float* fw2   = (const float*)d_in[3];
  const float* fb2   = (const float*)d_in[4];
  const float* decay = (const float*)d_in[5];
  const float* bias  = (const float*)d_in[6];
  const float* ipw   = (const float*)d_in[7];
  const float* ipb   = (const float*)d_in[8];
  const float* sw    = (const float*)d_in[9];
  const float* sb    = (const float*)d_in[10];
  const float* ow    = (const float*)d_in[11];
  const float* ob    = (const float*)d_in[12];
  float* out = (float*)d_out;

  char* ws = (char*)d_ws;
  u16*   up_t  = (u16*)(ws);                                // 75,497,472 B
  float* hH    = (float*)(ws + 75497472);                   // 100,663,296 B
  u16*   u_bf  = (u16*)(ws + 176160768);                    // 25,165,824 B
  u16*   ipw_t = (u16*)(ws + 201326592);                    // 3,538,944 B
  u16*   ow_t  = (u16*)(ws + 204865536);                    // 1,179,648 B
  u16*   vt_t  = (u16*)(ws + 206045184);                    // 25,165,824 B
  // filter-path scratch in the up_t region (dead until gemm1 runs later):
  u16*   hidb  = (u16*)(ws);                                // 2,097,152 B
  u16*   w2t   = (u16*)(ws + 2097152);                      //   196,608 B

  cast_bf16_kernel<<<dim3(12288), 256, 0, stream>>>(u, u_bf, (2 * L_SEQ * D_DIM) / 4);
  transpose_cast_kernel<<<dim3(C_IN / 32, D_DIM / 32), 256, 0, stream>>>(ipw, ipw_t, D_DIM, C_IN);
  transpose_cast_kernel<<<dim3(D_DIM / 32, F_DIM / 32), 256, 0, stream>>>(ow, ow_t, F_DIM, D_DIM);

  // filter path: hid (bf16) -> w2^T (bf16) -> MFMA h-GEMM (+decay epilogue) -> FFT
  hid_gen_kernel<<<dim3(NFFT / 16), 256, 0, stream>>>(fw1, fb1, hidb);
  transpose_cast_kernel<<<dim3(1536 / 32, 64 / 32), 256, 0, stream>>>(fw2, w2t, 64, 1536);
  mfma_gemm_kernel<1536, 64, 2><<<dim3(NFFT / 128, 1536 / 128), 256, 0, stream>>>(
      hidb, w2t, fb2, hH, decay);
  filter_fft_kernel<<<dim3(NORD * F_DIM), NT, 0, stream>>>(hH, bias);

  mfma_gemm_kernel<C_IN, D_DIM, 0><<<dim3(128, C_IN / 128), 256, 0, stream>>>(u_bf, ipw_t, ipb, up_t, nullptr);
  fftconv_kernel<<<dim3(F_DIM), NT, 0, stream>>>(up_t, hH, sw, sb);
  transpose_v_kernel<<<dim3(NFFT / 64, F_DIM / 64), 256, 0, stream>>>((const u16*)hH, vt_t);
  mfma_gemm_kernel<D_DIM, F_DIM, 1><<<dim3(128, D_DIM / 128), 256, 0, stream>>>(vt_t, ow_t, ob, out, nullptr);
}